// Round 6
// baseline (523.200 us; speedup 1.0000x reference)
//
#include <hip/hip_runtime.h>

// ---------------------------------------------------------------------------
// TurboQuantAttention — round 8 (= round 7 resubmitted after infra failure).
// Round-2 launch shape (grid 512 = head x qt, proven ~25MB FETCH); occupancy
// fixed INTRA-block: 512-thread blocks, 8 waves = (qg 0..3) x (kh 0..1).
// Each wave: 32 q-rows x 1024 keys. Per tile-step the block DMAs a 32KB
// package {K0|K1|V0|V1} into double-buffered LDS (4 DMAs/wave, vmcnt(0)+raw
// barrier per step). Key-half partials combine in LDS at the epilogue
// (static softmax bound -> exact), so global traffic is identical to
// round 2. 2 blocks/CU x 8 waves = 4 waves/SIMD.
// ---------------------------------------------------------------------------

typedef float    f32x4  __attribute__((ext_vector_type(4)));
typedef float    f32x16 __attribute__((ext_vector_type(16)));
typedef __bf16   bf16x8 __attribute__((ext_vector_type(8)));
typedef __bf16   bf16x4 __attribute__((ext_vector_type(4)));
typedef _Float16 f16x8  __attribute__((ext_vector_type(8)));
typedef unsigned long long u64;

#define SLEN 2048
#define DH   128

static __device__ __forceinline__ f32x16 zero16() {
  f32x16 z;
#pragma unroll
  for (int i = 0; i < 16; ++i) z[i] = 0.f;
  return z;
}

static __device__ __forceinline__ f32x16 mfma_bf16_32x32x16(bf16x8 a, bf16x8 b, f32x16 c) {
  return __builtin_amdgcn_mfma_f32_32x32x16_bf16(a, b, c, 0, 0, 0);
}
static __device__ __forceinline__ f32x16 mfma_f16_32x32x16(f16x8 a, f16x8 b, f32x16 c) {
  return __builtin_amdgcn_mfma_f32_32x32x16_f16(a, b, c, 0, 0, 0);
}

// async global->LDS, 16B per lane; lds base is wave-uniform, lane i lands at +i*16
static __device__ __forceinline__ void lds_dma16(const void* g, void* l) {
  __builtin_amdgcn_global_load_lds(
      (const __attribute__((address_space(1))) void*)(unsigned long long)g,
      (__attribute__((address_space(3))) void*)(unsigned int)(unsigned long long)l,
      16, 0, 0);
}

// quantize->dequantize one element, op-order identical to reference (fp32)
static __device__ __forceinline__ float qdq(float xr, float xmax, float qs) {
  float xs = xr / xmax * 3.5f;
  float xq = rintf(xs * 4.0f) * 0.25f;
  xq = fminf(3.5f, fmaxf(-3.5f, xq));
  float res = xs - xq;
  float sg = (res > 0.0f) ? 1.0f : ((res < 0.0f) ? -1.0f : 0.0f);
  float xc = xq + sg * qs * xmax;
  return xc / 3.5f * xmax;
}

static __device__ __forceinline__ unsigned short bfbits(float f) {
  __bf16 b = (__bf16)f;
  return __builtin_bit_cast(unsigned short, b);
}

// ---------------------------------------------------------------------------
// prep_R: split R (fp32 128x128) into f16 hi/lo, row-major and transposed.
// ---------------------------------------------------------------------------
__global__ __launch_bounds__(256) void prep_R(
    const float* __restrict__ R, _Float16* __restrict__ Bhi,
    _Float16* __restrict__ Blo, _Float16* __restrict__ BhiT,
    _Float16* __restrict__ BloT)
{
  int i = blockIdx.x * 256 + threadIdx.x;   // 0..16383
  int kk = i >> 7, n = i & 127;
  float r = R[i];
  _Float16 h = (_Float16)r;
  _Float16 l = (_Float16)(r - (float)h);
  Bhi[i] = h; Blo[i] = l;
  BhiT[n * 128 + kk] = h; BloT[n * 128 + kk] = l;
}

// ---------------------------------------------------------------------------
// rot_body: C = X(65536x128) @ B^T. NT=3: f16 hi/lo 3-term; NT=1: single pass.
// MODE 0: fp32 out + per-wave absmax -> part[bid*4+wave]
// MODE 1: bf16 out scaled by log2(e)/sqrt(128) + fused row norms -> qn (q)
// MODE 2: fp32 out                                               (unrotate)
// ---------------------------------------------------------------------------
template<int NT, int MODE>
static __device__ __forceinline__ void rot_body(
    const float* __restrict__ X, const _Float16* __restrict__ Gh,
    const _Float16* __restrict__ Gl, void* __restrict__ OUTv,
    float* __restrict__ part, float* __restrict__ qn, int bid)
{
  __shared__ _Float16 BH[128 * 128];
  __shared__ _Float16 BL[(NT == 3) ? 128 * 128 : 8];

  const int tid = threadIdx.x, wave = tid >> 6, lane = tid & 63;
  const int r31 = lane & 31, hi = lane >> 5;
  const long r0 = (long)bid * 128;

  // stage B via DMA, XOR-swizzled at 16B-chunk granularity
#pragma unroll
  for (int u = 0; u < 8; ++u) {
    int c = (wave * 8 + u) * 64 + lane;
    int n = c >> 4, p = c & 15, ch = p ^ (n & 7);
    lds_dma16(Gh + n * 128 + ch * 8, BH + (wave * 8 + u) * 512);
    if constexpr (NT == 3)
      lds_dma16(Gl + n * 128 + ch * 8, BL + (wave * 8 + u) * 512);
  }

  // A: load X rows direct from global, split f16 hi/lo in regs
  const long rowg = r0 + wave * 32 + r31;
  f16x8 ah[8], al[8];
#pragma unroll
  for (int t = 0; t < 8; ++t) {
    f32x4 x0 = *(const f32x4*)&X[rowg * 128 + t * 16 + hi * 8];
    f32x4 x1 = *(const f32x4*)&X[rowg * 128 + t * 16 + hi * 8 + 4];
#pragma unroll
    for (int j = 0; j < 4; ++j) {
      _Float16 h0 = (_Float16)x0[j]; ah[t][j] = h0;
      _Float16 h1 = (_Float16)x1[j]; ah[t][4 + j] = h1;
      if constexpr (NT == 3) {
        al[t][j]     = (_Float16)(x0[j] - (float)h0);
        al[t][4 + j] = (_Float16)(x1[j] - (float)h1);
      }
    }
  }
  __syncthreads();

  f32x16 acc[4];
#pragma unroll
  for (int ct = 0; ct < 4; ++ct) acc[ct] = zero16();

#pragma unroll
  for (int ct = 0; ct < 4; ++ct) {
#pragma unroll
    for (int t = 0; t < 8; ++t) {
      int idx = (ct * 32 + r31) * 128 + (((2 * t + hi) ^ (r31 & 7)) * 8);
      f16x8 bh = *(const f16x8*)&BH[idx];
      acc[ct] = mfma_f16_32x32x16(ah[t], bh, acc[ct]);
      if constexpr (NT == 3) {
        f16x8 bl = *(const f16x8*)&BL[idx];
        acc[ct] = mfma_f16_32x32x16(ah[t], bl, acc[ct]);
        acc[ct] = mfma_f16_32x32x16(al[t], bh, acc[ct]);
      }
    }
  }

  if constexpr (MODE == 0) {
    float* OUT = (float*)OUTv;
    float am = 0.f;
#pragma unroll
    for (int ct = 0; ct < 4; ++ct)
#pragma unroll
      for (int r = 0; r < 16; ++r) {
        long grow = r0 + wave * 32 + (r & 3) + 8 * (r >> 2) + 4 * hi;
        float v = acc[ct][r];
        OUT[grow * 128 + ct * 32 + r31] = v;
        am = fmaxf(am, fabsf(v));
      }
#pragma unroll
    for (int m = 1; m <= 32; m <<= 1) am = fmaxf(am, __shfl_xor(am, m, 64));
    if (lane == 0) part[bid * 4 + wave] = am;
  } else if constexpr (MODE == 1) {
    __bf16* OUT = (__bf16*)OUTv;
    const float sc = 0.12751743342f;   // log2(e)/sqrt(128): exp2-domain scores
    float rs[16];
#pragma unroll
    for (int r = 0; r < 16; ++r) rs[r] = 0.f;
#pragma unroll
    for (int ct = 0; ct < 4; ++ct)
#pragma unroll
      for (int r = 0; r < 16; ++r) {
        long grow = r0 + wave * 32 + (r & 3) + 8 * (r >> 2) + 4 * hi;
        __bf16 b = (__bf16)(acc[ct][r] * sc);
        OUT[grow * 128 + ct * 32 + r31] = b;
        float fb = (float)b;
        rs[r] += fb * fb;
      }
    // row sumsq: reduce across the 32 lanes of this hi-half, then one lane writes
#pragma unroll
    for (int r = 0; r < 16; ++r) {
#pragma unroll
      for (int msk = 1; msk <= 16; msk <<= 1) rs[r] += __shfl_xor(rs[r], msk, 64);
      if (r31 == r)
        qn[r0 + wave * 32 + (r & 3) + 8 * (r >> 2) + 4 * hi] = sqrtf(rs[r]);
    }
  } else {
    float* OUT = (float*)OUTv;
#pragma unroll
    for (int ct = 0; ct < 4; ++ct)
#pragma unroll
      for (int r = 0; r < 16; ++r) {
        long grow = r0 + wave * 32 + (r & 3) + 8 * (r >> 2) + 4 * hi;
        OUT[grow * 128 + ct * 32 + r31] = acc[ct][r];
      }
  }
}

// merged k+v rotation: blocks 0..511 -> k, 512..1023 -> v
__global__ __launch_bounds__(256) void rot_kv_kernel(
    const float* __restrict__ K, const float* __restrict__ V,
    const _Float16* __restrict__ Gh, const _Float16* __restrict__ Gl,
    float* __restrict__ kr, float* __restrict__ vr,
    float* __restrict__ kpart, float* __restrict__ vpart)
{
  const bool isv = blockIdx.x >= 512;
  rot_body<3, 0>(isv ? V : K, Gh, Gl, isv ? (void*)vr : (void*)kr,
                 isv ? vpart : kpart, nullptr, blockIdx.x & 511);
}

__global__ __launch_bounds__(256) void rot_q_kernel(
    const float* __restrict__ X, const _Float16* __restrict__ Gh,
    const _Float16* __restrict__ Gl, __bf16* __restrict__ qb,
    float* __restrict__ qn)
{
  rot_body<1, 1>(X, Gh, Gl, (void*)qb, nullptr, qn, blockIdx.x);
}

__global__ __launch_bounds__(256) void rot_o_kernel(
    const float* __restrict__ X, const _Float16* __restrict__ Gh,
    const _Float16* __restrict__ Gl, float* __restrict__ out)
{
  rot_body<1, 2>(X, Gh, Gl, (void*)out, nullptr, nullptr, blockIdx.x);
}

// ---------------------------------------------------------------------------
// quantize+dequant v -> per-tile x16 B-fragment layout:
//   per 32-key tile (8KB): 16B unit u = (half*2+hi)*128 + d holds keys
//   {16*half+4*hi+(0..3), 16*half+4*hi+8+(0..3)} at row d.
// ---------------------------------------------------------------------------
__global__ __launch_bounds__(256) void quantize_vt_kernel(
    const float* __restrict__ vr, const float* __restrict__ vpart,
    const float* __restrict__ qjl, u64* __restrict__ vdt2)
{
  __shared__ unsigned int Ts32[128][18];
  __shared__ float sm[4];
  const int tid = threadIdx.x;

  float m = 0.f;
  for (int i = tid; i < 2048; i += 256) m = fmaxf(m, vpart[i]);
#pragma unroll
  for (int msk = 1; msk <= 32; msk <<= 1) m = fmaxf(m, __shfl_xor(m, msk, 64));
  if ((tid & 63) == 0) sm[tid >> 6] = m;
  __syncthreads();
  const float xmax = fmaxf(fmaxf(sm[0], sm[1]), fmaxf(sm[2], sm[3])) + 1e-8f;
  const float qs = qjl[0];

  const int bh = blockIdx.x >> 6, blk = blockIdx.x & 63;
  const int s0 = blk * 32;
  const int sp  = tid & 15;
  const int dch = tid >> 4;
  const long rb = (long)bh * SLEN + s0;
  const float* p0 = &vr[(rb + sp * 2    ) * 128 + dch * 8];
  const float* p1 = &vr[(rb + sp * 2 + 1) * 128 + dch * 8];
#pragma unroll
  for (int j = 0; j < 8; ++j) {
    unsigned a = bfbits(qdq(p0[j], xmax, qs));
    unsigned b = bfbits(qdq(p1[j], xmax, qs));
    Ts32[dch * 8 + j][sp] = a | (b << 16);   // keys (s0+2sp, s0+2sp+1), row dch*8+j
  }
  __syncthreads();
  const long obase = (long)(bh * 64 + blk) * 1024;   // u64 units per tile
#pragma unroll
  for (int uu = 0; uu < 2; ++uu) {
    int u_ = uu * 256 + tid;                 // 0..511: (half,hi,d)
    int half = u_ >> 8, hi = (u_ >> 7) & 1, d = u_ & 127;
    u64 qlo = *(const u64*)&Ts32[d][2 * (half * 4 + hi)];
    u64 qhi = *(const u64*)&Ts32[d][2 * (half * 4 + hi + 2)];
    vdt2[obase + u_ * 2    ] = qlo;
    vdt2[obase + u_ * 2 + 1] = qhi;
  }
}

// elementwise quantize+dequant k -> bf16 natural layout (+ inline kmax reduce)
__global__ __launch_bounds__(256) void quantize_k_kernel(
    const float* __restrict__ kr, const float* __restrict__ kpart,
    const float* __restrict__ qjl, __bf16* __restrict__ out)
{
  __shared__ float sm[4];
  const int tid = threadIdx.x;
  float m = 0.f;
  for (int i = tid; i < 2048; i += 256) m = fmaxf(m, kpart[i]);
#pragma unroll
  for (int msk = 1; msk <= 32; msk <<= 1) m = fmaxf(m, __shfl_xor(m, msk, 64));
  if ((tid & 63) == 0) sm[tid >> 6] = m;
  __syncthreads();
  const float xmax = fmaxf(fmaxf(sm[0], sm[1]), fmaxf(sm[2], sm[3])) + 1e-8f;
  const float qs = qjl[0];

  long i = ((long)blockIdx.x * 256 + tid) * 4;
  f32x4 x = *(const f32x4*)&kr[i];
  bf16x4 ov;
#pragma unroll
  for (int j = 0; j < 4; ++j) ov[j] = (__bf16)qdq(x[j], xmax, qs);
  *(bf16x4*)&out[i] = ov;
}

// ---------------------------------------------------------------------------
// attn2: 8-wave flash attention. grid 512 = {qt 0..15} x {head 0..31};
// wave = (kh = wave>>2, qg = wave&3). Per tile-step: 32KB package
// {K0|K1|V0|V1} DMA'd into double-buffered LDS (chunk c = wave*4+j), raw
// barrier + per-wave vmcnt(0). Epilogue: kh=1 waves dump acc into LDS,
// kh=0 waves add, normalize by (lsum0+lsum1), write orot.
// ---------------------------------------------------------------------------
__global__ __launch_bounds__(512, 4) void attn2(
    const __bf16* __restrict__ qb, const __bf16* __restrict__ kd,
    const u64* __restrict__ vdt2, const float* __restrict__ qn,
    const float* __restrict__ kpart, const float* __restrict__ qjl,
    float* __restrict__ orot)
{
  __shared__ __attribute__((aligned(16))) char TileBuf[2][32768];
  __shared__ float Ls[8][32];
  __shared__ float sm[8];

  const int tid = threadIdx.x, wave = tid >> 6, lane = tid & 63;
  const int r31 = lane & 31, hi = lane >> 5;
  const int qg = wave & 3, kh = wave >> 2;
  const int head = blockIdx.x & 31, qt = blockIdx.x >> 5;
  const long hrow = (long)head * SLEN;
  const int qrow0 = qt * 128 + qg * 32;

  // block-local reduce of kpart (identical result to a global reduce)
  float km = 0.f;
  for (int i = tid; i < 2048; i += 512) km = fmaxf(km, kpart[i]);
#pragma unroll
  for (int m = 1; m <= 32; m <<= 1) km = fmaxf(km, __shfl_xor(km, m, 64));
  if (lane == 0) sm[wave] = km;
  __syncthreads();
  float xmax = sm[0];
#pragma unroll
  for (int i = 1; i < 8; ++i) xmax = fmaxf(xmax, sm[i]);
  xmax += 1e-8f;
  const float Bk = 11.313708499f * ((3.5f + qjl[0] * xmax) * xmax / 3.5f) * 1.02f * 0.5f;

  // Q fragments, B-layout of 32x32x16 (pre-scaled by log2e/sqrt(128))
  bf16x8 qf[8];
#pragma unroll
  for (int t = 0; t < 8; ++t)
    qf[t] = *(const bf16x8*)&qb[(hrow + qrow0 + r31) * DH + t * 16 + hi * 8];
  const float mqneg = -(qn[hrow + qrow0 + r31] * Bk);   // log2-domain bound

  // Ks LDS read byte-offsets (tile-invariant): chunk (2t+hi) XOR (row&7)
  int koff[8];
#pragma unroll
  for (int t = 0; t < 8; ++t)
    koff[t] = r31 * 256 + (((2 * t + hi) ^ (r31 & 7)) << 4);

  // V LDS read base, u64 units within an 8KB half-tile:
  // 16B unit (half,hi,dt,r31) at u64 idx half*512 + hi*256 + dt*64 + 2*r31
  const int vbse = hi * 256 + 2 * r31;

  // staging: this wave owns package chunks c = wave*4 + j (1KB each).
  // package layout (bytes): [0,8K)=K half0, [8K,16K)=K half1,
  //                         [16K,24K)=V half0, [24K,32K)=V half1.
  const char* srcj[4]; int dstj[4];
#pragma unroll
  for (int j = 0; j < 4; ++j) {
    const int c = wave * 4 + j;
    dstj[j] = c * 1024;
    if (c < 16) {               // K: swizzle-compensated source
      const int half = c >> 3;
      const int i0 = (c & 7) * 64 + lane;        // 16B-chunk idx in half-tile
      const int row = i0 >> 4, ch = (i0 & 15) ^ (row & 7);
      srcj[j] = (const char*)(kd + (hrow + half * 1024 + row) * DH + ch * 8);
    } else {                    // V: linear copy of pre-permuted tile
      const int half = (c >> 3) & 1, cc = c & 7;
      srcj[j] = (const char*)vdt2 + ((long)(head * 64 + half * 32)) * 8192
                + cc * 1024 + lane * 16;
    }
  }

  // stage block-local tile T into buffer B (both K/V sources advance 8KB/tile)
  auto STAGE = [&](int B, int T) {
    const long o = (long)T * 8192;
#pragma unroll
    for (int j = 0; j < 4; ++j)
      lds_dma16(srcj[j] + o, &TileBuf[B][dstj[j]]);
  };

  STAGE(0, 0);

  f32x16 acc[4];
#pragma unroll
  for (int dt = 0; dt < 4; ++dt) acc[dt] = zero16();
  float ls0 = 0.f, ls1 = 0.f, ls2 = 0.f, ls3 = 0.f;

#pragma unroll 2
  for (int t = 0; t < 32; ++t) {
    const int B = t & 1;
    asm volatile("s_waitcnt vmcnt(0)" ::: "memory");   // own DMAs for tile t landed
    __builtin_amdgcn_s_barrier();                      // => all waves' DMAs landed
    asm volatile("" ::: "memory");
    if (t < 31) STAGE(B ^ 1, t + 1);                   // flight = this compute phase

    // S^T = K Q^T: single 8-MFMA chain, s starts at -Mq
    f32x16 s;
#pragma unroll
    for (int r = 0; r < 16; ++r) s[r] = mqneg;
    const char* kb = &TileBuf[B][kh * 8192];
    __builtin_amdgcn_s_setprio(1);
#pragma unroll
    for (int tt = 0; tt < 8; ++tt) {
      bf16x8 ka = *(const bf16x8*)(kb + koff[tt]);
      s = mfma_bf16_32x32x16(ka, qf[tt], s);
    }
    __builtin_amdgcn_s_setprio(0);

    // softmax numerator, P in registers
    float p[16];
#pragma unroll
    for (int r = 0; r < 16; ++r) p[r] = __builtin_amdgcn_exp2f(s[r]);
#pragma unroll
    for (int r = 0; r < 16; r += 4) {
      ls0 += p[r]; ls1 += p[r + 1]; ls2 += p[r + 2]; ls3 += p[r + 3];
    }
    bf16x8 pa, pb;
#pragma unroll
    for (int jj = 0; jj < 8; ++jj) { pa[jj] = (__bf16)p[jj]; pb[jj] = (__bf16)p[8 + jj]; }

    // PV: O[q][d] += P V  (x16, B-fragments from permuted V half-tile)
    const u64* vb = (const u64*)&TileBuf[B][16384 + kh * 8192] + vbse;
    __builtin_amdgcn_s_setprio(1);
#pragma unroll
    for (int dt = 0; dt < 4; ++dt)
      acc[dt] = mfma_bf16_32x32x16(pa, *(const bf16x8*)(vb + dt * 64), acc[dt]);
#pragma unroll
    for (int dt = 0; dt < 4; ++dt)
      acc[dt] = mfma_bf16_32x32x16(pb, *(const bf16x8*)(vb + 512 + dt * 64), acc[dt]);
    __builtin_amdgcn_s_setprio(0);
  }

  // per-wave lsum (fold hi halves) -> Ls[wave][qrow]
  float lsum = (ls0 + ls1) + (ls2 + ls3);
  lsum += __shfl_xor(lsum, 32, 64);
  if (hi == 0) Ls[wave][r31] = lsum;
  __syncthreads();                        // also: TileBuf free for exchange

  float* exch = (float*)TileBuf;          // 64KB = 4 x 16KB per-qg regions
  if (kh == 1) {
#pragma unroll
    for (int dt = 0; dt < 4; ++dt)
#pragma unroll
      for (int r = 0; r < 16; ++r)
        exch[qg * 4096 + (dt * 16 + r) * 64 + lane] = acc[dt][r];
  }
  __syncthreads();
  if (kh == 0) {
#pragma unroll
    for (int r = 0; r < 16; ++r) {
      const int qr = (r & 3) + 8 * (r >> 2) + 4 * hi;
      const float rinv = 1.0f / (Ls[qg][qr] + Ls[qg + 4][qr]);
#pragma unroll
      for (int dt = 0; dt < 4; ++dt)
        orot[(hrow + qrow0 + qr) * DH + dt * 32 + r31] =
            (acc[dt][r] + exch[qg * 4096 + (dt * 16 + r) * 64 + lane]) * rinv;
    }
  }
}

// ---------------------------------------------------------------------------
extern "C" void kernel_launch(void* const* d_in, const int* in_sizes, int n_in,
                              void* d_out, int out_size, void* d_ws, size_t ws_size,
                              hipStream_t stream)
{
  const float* q   = (const float*)d_in[0];
  const float* k   = (const float*)d_in[1];
  const float* v   = (const float*)d_in[2];
  const float* R   = (const float*)d_in[3];
  const float* qjl = (const float*)d_in[4];

  char* ws = (char*)d_ws;
  float* kpart = (float*)ws;                      // [2048]
  float* vpart = (float*)(ws + 8192);             // [2048]
  _Float16* Bhi  = (_Float16*)(ws + 32768);       // R row-major f16 hi (32KB)
  _Float16* Blo  = (_Float16*)(ws + 65536);
  _Float16* BhiT = (_Float16*)(ws + 98304);       // R^T f16 hi
  _Float16* BloT = (_Float16*)(ws + 131072);
  float* qn = (float*)(ws + 163840);              // [65536] (256KB)
  char* base = ws + 425984;
  __bf16* qb   = (__bf16*)base;                                 // 16 MiB
  float*  kr   = (float*)(base + (16u << 20));                  // 32 MiB
  float*  vr   = (float*)(base + (48u << 20));                  // 32 MiB
  u64*    vdt2 = (u64*)(base + (80u << 20));                    // 16 MiB
  __bf16* kd   = (__bf16*)vr;   // reuse vr after quantize_vt consumed it
  float* orot  = kr;            // reuse kr after quantize_k consumed it

  dim3 b256(256), b512(512);
  prep_R<<<64, b256, 0, stream>>>(R, Bhi, Blo, BhiT, BloT);
  rot_kv_kernel<<<1024, b256, 0, stream>>>(k, v, BhiT, BloT, kr, vr, kpart, vpart);
  rot_q_kernel<<<512, b256, 0, stream>>>(q, BhiT, BloT, qb, qn);
  quantize_vt_kernel<<<2048, b256, 0, stream>>>(vr, vpart, qjl, vdt2);
  quantize_k_kernel<<<8192, b256, 0, stream>>>(kr, kpart, qjl, kd);
  attn2<<<512, b512, 0, stream>>>(qb, kd, vdt2, qn, kpart, qjl, orot);
  rot_o_kernel<<<512, b256, 0, stream>>>(orot, Bhi, Blo, (float*)d_out);
}

// Round 9
// 412.366 us; speedup vs baseline: 1.2688x; 1.2688x over previous
//
#include <hip/hip_runtime.h>

// ---------------------------------------------------------------------------
// TurboQuantAttention — round 11.
// Back to the verified 281-us pipeline (prep_R, rot_kv NT3, rot_q, quantize_vt,
// quantize_k, attn2, rot_o). Two changes only:
//  1) attn2 = round-6-verified single-tile double-buffered structure at the
//     verified grid 512 (NO kh split): 33KB LDS -> 4 blocks/CU = 4 waves/SIMD
//     (the occupancy fix), identical global traffic to the 79-us version.
//  2) attn2 writes orot as f16 (bit-identical to rot_o's old f32->f16 load
//     conversion); rot_o reads f16 -> halves its input traffic.
// Cooperative launch abandoned (two bit-identical failures = launches never
// ran in this harness).
// ---------------------------------------------------------------------------

typedef float    f32x4  __attribute__((ext_vector_type(4)));
typedef float    f32x16 __attribute__((ext_vector_type(16)));
typedef __bf16   bf16x8 __attribute__((ext_vector_type(8)));
typedef __bf16   bf16x4 __attribute__((ext_vector_type(4)));
typedef _Float16 f16x8  __attribute__((ext_vector_type(8)));
typedef unsigned long long u64;

#define SLEN 2048
#define DH   128

static __device__ __forceinline__ f32x16 zero16() {
  f32x16 z;
#pragma unroll
  for (int i = 0; i < 16; ++i) z[i] = 0.f;
  return z;
}

static __device__ __forceinline__ f32x16 mfma_bf16_32x32x16(bf16x8 a, bf16x8 b, f32x16 c) {
  return __builtin_amdgcn_mfma_f32_32x32x16_bf16(a, b, c, 0, 0, 0);
}
static __device__ __forceinline__ f32x16 mfma_f16_32x32x16(f16x8 a, f16x8 b, f32x16 c) {
  return __builtin_amdgcn_mfma_f32_32x32x16_f16(a, b, c, 0, 0, 0);
}

// async global->LDS, 16B per lane; lds base is wave-uniform, lane i lands at +i*16
static __device__ __forceinline__ void lds_dma16(const void* g, void* l) {
  __builtin_amdgcn_global_load_lds(
      (const __attribute__((address_space(1))) void*)(unsigned long long)g,
      (__attribute__((address_space(3))) void*)(unsigned int)(unsigned long long)l,
      16, 0, 0);
}

// quantize->dequantize one element, op-order identical to reference (fp32)
static __device__ __forceinline__ float qdq(float xr, float xmax, float qs) {
  float xs = xr / xmax * 3.5f;
  float xq = rintf(xs * 4.0f) * 0.25f;
  xq = fminf(3.5f, fmaxf(-3.5f, xq));
  float res = xs - xq;
  float sg = (res > 0.0f) ? 1.0f : ((res < 0.0f) ? -1.0f : 0.0f);
  float xc = xq + sg * qs * xmax;
  return xc / 3.5f * xmax;
}

static __device__ __forceinline__ unsigned short bfbits(float f) {
  __bf16 b = (__bf16)f;
  return __builtin_bit_cast(unsigned short, b);
}

// ---------------------------------------------------------------------------
// prep_R: split R (fp32 128x128) into f16 hi/lo, row-major and transposed.
// ---------------------------------------------------------------------------
__global__ __launch_bounds__(256) void prep_R(
    const float* __restrict__ R, _Float16* __restrict__ Bhi,
    _Float16* __restrict__ Blo, _Float16* __restrict__ BhiT,
    _Float16* __restrict__ BloT)
{
  int i = blockIdx.x * 256 + threadIdx.x;   // 0..16383
  int kk = i >> 7, n = i & 127;
  float r = R[i];
  _Float16 h = (_Float16)r;
  _Float16 l = (_Float16)(r - (float)h);
  Bhi[i] = h; Blo[i] = l;
  BhiT[n * 128 + kk] = h; BloT[n * 128 + kk] = l;
}

// ---------------------------------------------------------------------------
// rot_body: C = X(65536x128) @ B^T. NT=3: f16 hi/lo 3-term; NT=1: single pass.
// MODE 0: fp32 out + per-wave absmax -> part[bid*4+wave]
// MODE 1: bf16 out scaled by log2(e)/sqrt(128) + fused row norms -> qn (q)
// ---------------------------------------------------------------------------
template<int NT, int MODE>
static __device__ __forceinline__ void rot_body(
    const float* __restrict__ X, const _Float16* __restrict__ Gh,
    const _Float16* __restrict__ Gl, void* __restrict__ OUTv,
    float* __restrict__ part, float* __restrict__ qn, int bid)
{
  __shared__ _Float16 BH[128 * 128];
  __shared__ _Float16 BL[(NT == 3) ? 128 * 128 : 8];

  const int tid = threadIdx.x, wave = tid >> 6, lane = tid & 63;
  const int r31 = lane & 31, hi = lane >> 5;
  const long r0 = (long)bid * 128;

  // stage B via DMA, XOR-swizzled at 16B-chunk granularity
#pragma unroll
  for (int u = 0; u < 8; ++u) {
    int c = (wave * 8 + u) * 64 + lane;
    int n = c >> 4, p = c & 15, ch = p ^ (n & 7);
    lds_dma16(Gh + n * 128 + ch * 8, BH + (wave * 8 + u) * 512);
    if constexpr (NT == 3)
      lds_dma16(Gl + n * 128 + ch * 8, BL + (wave * 8 + u) * 512);
  }

  // A: load X rows direct from global, split f16 hi/lo in regs
  const long rowg = r0 + wave * 32 + r31;
  f16x8 ah[8], al[8];
#pragma unroll
  for (int t = 0; t < 8; ++t) {
    f32x4 x0 = *(const f32x4*)&X[rowg * 128 + t * 16 + hi * 8];
    f32x4 x1 = *(const f32x4*)&X[rowg * 128 + t * 16 + hi * 8 + 4];
#pragma unroll
    for (int j = 0; j < 4; ++j) {
      _Float16 h0 = (_Float16)x0[j]; ah[t][j] = h0;
      _Float16 h1 = (_Float16)x1[j]; ah[t][4 + j] = h1;
      if constexpr (NT == 3) {
        al[t][j]     = (_Float16)(x0[j] - (float)h0);
        al[t][4 + j] = (_Float16)(x1[j] - (float)h1);
      }
    }
  }
  __syncthreads();

  f32x16 acc[4];
#pragma unroll
  for (int ct = 0; ct < 4; ++ct) acc[ct] = zero16();

#pragma unroll
  for (int ct = 0; ct < 4; ++ct) {
#pragma unroll
    for (int t = 0; t < 8; ++t) {
      int idx = (ct * 32 + r31) * 128 + (((2 * t + hi) ^ (r31 & 7)) * 8);
      f16x8 bh = *(const f16x8*)&BH[idx];
      acc[ct] = mfma_f16_32x32x16(ah[t], bh, acc[ct]);
      if constexpr (NT == 3) {
        f16x8 bl = *(const f16x8*)&BL[idx];
        acc[ct] = mfma_f16_32x32x16(ah[t], bl, acc[ct]);
        acc[ct] = mfma_f16_32x32x16(al[t], bh, acc[ct]);
      }
    }
  }

  if constexpr (MODE == 0) {
    float* OUT = (float*)OUTv;
    float am = 0.f;
#pragma unroll
    for (int ct = 0; ct < 4; ++ct)
#pragma unroll
      for (int r = 0; r < 16; ++r) {
        long grow = r0 + wave * 32 + (r & 3) + 8 * (r >> 2) + 4 * hi;
        float v = acc[ct][r];
        OUT[grow * 128 + ct * 32 + r31] = v;
        am = fmaxf(am, fabsf(v));
      }
#pragma unroll
    for (int m = 1; m <= 32; m <<= 1) am = fmaxf(am, __shfl_xor(am, m, 64));
    if (lane == 0) part[bid * 4 + wave] = am;
  } else {
    __bf16* OUT = (__bf16*)OUTv;
    const float sc = 0.12751743342f;   // log2(e)/sqrt(128): exp2-domain scores
    float rs[16];
#pragma unroll
    for (int r = 0; r < 16; ++r) rs[r] = 0.f;
#pragma unroll
    for (int ct = 0; ct < 4; ++ct)
#pragma unroll
      for (int r = 0; r < 16; ++r) {
        long grow = r0 + wave * 32 + (r & 3) + 8 * (r >> 2) + 4 * hi;
        __bf16 b = (__bf16)(acc[ct][r] * sc);
        OUT[grow * 128 + ct * 32 + r31] = b;
        float fb = (float)b;
        rs[r] += fb * fb;
      }
    // row sumsq: reduce across the 32 lanes of this hi-half, then one lane writes
#pragma unroll
    for (int r = 0; r < 16; ++r) {
#pragma unroll
      for (int msk = 1; msk <= 16; msk <<= 1) rs[r] += __shfl_xor(rs[r], msk, 64);
      if (r31 == r)
        qn[r0 + wave * 32 + (r & 3) + 8 * (r >> 2) + 4 * hi] = sqrtf(rs[r]);
    }
  }
}

// merged k+v rotation: blocks 0..511 -> k, 512..1023 -> v
__global__ __launch_bounds__(256) void rot_kv_kernel(
    const float* __restrict__ K, const float* __restrict__ V,
    const _Float16* __restrict__ Gh, const _Float16* __restrict__ Gl,
    float* __restrict__ kr, float* __restrict__ vr,
    float* __restrict__ kpart, float* __restrict__ vpart)
{
  const bool isv = blockIdx.x >= 512;
  rot_body<3, 0>(isv ? V : K, Gh, Gl, isv ? (void*)vr : (void*)kr,
                 isv ? vpart : kpart, nullptr, blockIdx.x & 511);
}

__global__ __launch_bounds__(256) void rot_q_kernel(
    const float* __restrict__ X, const _Float16* __restrict__ Gh,
    const _Float16* __restrict__ Gl, __bf16* __restrict__ qb,
    float* __restrict__ qn)
{
  rot_body<1, 1>(X, Gh, Gl, (void*)qb, nullptr, qn, blockIdx.x);
}

// ---------------------------------------------------------------------------
// rot_o: y = x @ R from f16 input (attn2 now emits f16 orot — bit-identical
// to the old f32 store + f16 load-convert).
// ---------------------------------------------------------------------------
__global__ __launch_bounds__(256) void rot_o_kernel(
    const _Float16* __restrict__ X, const _Float16* __restrict__ Gh,
    float* __restrict__ OUT)
{
  __shared__ _Float16 BH[128 * 128];

  const int tid = threadIdx.x, wave = tid >> 6, lane = tid & 63;
  const int r31 = lane & 31, hi = lane >> 5;
  const long r0 = (long)blockIdx.x * 128;

#pragma unroll
  for (int u = 0; u < 8; ++u) {
    int c = (wave * 8 + u) * 64 + lane;
    int n = c >> 4, p = c & 15, ch = p ^ (n & 7);
    lds_dma16(Gh + n * 128 + ch * 8, BH + (wave * 8 + u) * 512);
  }

  const long rowg = r0 + wave * 32 + r31;
  f16x8 ah[8];
#pragma unroll
  for (int t = 0; t < 8; ++t)
    ah[t] = *(const f16x8*)&X[rowg * 128 + t * 16 + hi * 8];
  __syncthreads();

  f32x16 acc[4];
#pragma unroll
  for (int ct = 0; ct < 4; ++ct) acc[ct] = zero16();
#pragma unroll
  for (int ct = 0; ct < 4; ++ct) {
#pragma unroll
    for (int t = 0; t < 8; ++t) {
      int idx = (ct * 32 + r31) * 128 + (((2 * t + hi) ^ (r31 & 7)) * 8);
      f16x8 bh = *(const f16x8*)&BH[idx];
      acc[ct] = mfma_f16_32x32x16(ah[t], bh, acc[ct]);
    }
  }
#pragma unroll
  for (int ct = 0; ct < 4; ++ct)
#pragma unroll
    for (int r = 0; r < 16; ++r) {
      long grow = r0 + wave * 32 + (r & 3) + 8 * (r >> 2) + 4 * hi;
      OUT[grow * 128 + ct * 32 + r31] = acc[ct][r];
    }
}

// ---------------------------------------------------------------------------
// quantize+dequant v -> per-tile x16 B-fragment layout:
//   per 32-key tile (8KB): 16B unit u = (half*2+hi)*128 + d holds keys
//   {16*half+4*hi+(0..3), 16*half+4*hi+8+(0..3)} at row d.
// ---------------------------------------------------------------------------
__global__ __launch_bounds__(256) void quantize_vt_kernel(
    const float* __restrict__ vr, const float* __restrict__ vpart,
    const float* __restrict__ qjl, u64* __restrict__ vdt2)
{
  __shared__ unsigned int Ts32[128][18];
  __shared__ float sm[4];
  const int tid = threadIdx.x;

  float m = 0.f;
  for (int i = tid; i < 2048; i += 256) m = fmaxf(m, vpart[i]);
#pragma unroll
  for (int msk = 1; msk <= 32; msk <<= 1) m = fmaxf(m, __shfl_xor(m, msk, 64));
  if ((tid & 63) == 0) sm[tid >> 6] = m;
  __syncthreads();
  const float xmax = fmaxf(fmaxf(sm[0], sm[1]), fmaxf(sm[2], sm[3])) + 1e-8f;
  const float qs = qjl[0];

  const int bh = blockIdx.x >> 6, blk = blockIdx.x & 63;
  const int s0 = blk * 32;
  const int sp  = tid & 15;
  const int dch = tid >> 4;
  const long rb = (long)bh * SLEN + s0;
  const float* p0 = &vr[(rb + sp * 2    ) * 128 + dch * 8];
  const float* p1 = &vr[(rb + sp * 2 + 1) * 128 + dch * 8];
#pragma unroll
  for (int j = 0; j < 8; ++j) {
    unsigned a = bfbits(qdq(p0[j], xmax, qs));
    unsigned b = bfbits(qdq(p1[j], xmax, qs));
    Ts32[dch * 8 + j][sp] = a | (b << 16);   // keys (s0+2sp, s0+2sp+1), row dch*8+j
  }
  __syncthreads();
  const long obase = (long)(bh * 64 + blk) * 1024;   // u64 units per tile
#pragma unroll
  for (int uu = 0; uu < 2; ++uu) {
    int u_ = uu * 256 + tid;                 // 0..511: (half,hi,d)
    int half = u_ >> 8, hi = (u_ >> 7) & 1, d = u_ & 127;
    u64 qlo = *(const u64*)&Ts32[d][2 * (half * 4 + hi)];
    u64 qhi = *(const u64*)&Ts32[d][2 * (half * 4 + hi + 2)];
    vdt2[obase + u_ * 2    ] = qlo;
    vdt2[obase + u_ * 2 + 1] = qhi;
  }
}

// elementwise quantize+dequant k -> bf16 natural layout (+ inline kmax reduce)
__global__ __launch_bounds__(256) void quantize_k_kernel(
    const float* __restrict__ kr, const float* __restrict__ kpart,
    const float* __restrict__ qjl, __bf16* __restrict__ out)
{
  __shared__ float sm[4];
  const int tid = threadIdx.x;
  float m = 0.f;
  for (int i = tid; i < 2048; i += 256) m = fmaxf(m, kpart[i]);
#pragma unroll
  for (int msk = 1; msk <= 32; msk <<= 1) m = fmaxf(m, __shfl_xor(m, msk, 64));
  if ((tid & 63) == 0) sm[tid >> 6] = m;
  __syncthreads();
  const float xmax = fmaxf(fmaxf(sm[0], sm[1]), fmaxf(sm[2], sm[3])) + 1e-8f;
  const float qs = qjl[0];

  long i = ((long)blockIdx.x * 256 + tid) * 4;
  f32x4 x = *(const f32x4*)&kr[i];
  bf16x4 ov;
#pragma unroll
  for (int j = 0; j < 4; ++j) ov[j] = (__bf16)qdq(x[j], xmax, qs);
  *(bf16x4*)&out[i] = ov;
}

// ---------------------------------------------------------------------------
// attn2: flash attention, grid 512 = {qt} x {head} (verified traffic shape),
// single-tile double-buffered DMA pipeline (33KB LDS -> 4 blocks/CU =
// 4 waves/SIMD). Per tile: vmcnt(0)+raw barrier, prefetch tile t+1.
// QK single 8-MFMA chain (s init -Mq), exp2 softmax, x16 PV via permuted V
// (round-6-verified addressing). Emits f16 orot.
// ---------------------------------------------------------------------------
__global__ __launch_bounds__(256, 4) void attn2(
    const __bf16* __restrict__ qb, const __bf16* __restrict__ kd,
    const u64* __restrict__ vdt2, const float* __restrict__ qn,
    const float* __restrict__ kpart, const float* __restrict__ qjl,
    _Float16* __restrict__ orot)
{
  __shared__ __attribute__((aligned(16))) __bf16 Ks[2][32 * DH]; // 16KB
  __shared__ __attribute__((aligned(16))) u64   Vt[2][1024];     // 16KB
  __shared__ float Ls[4][32];
  __shared__ float sm[4];

  const int tid = threadIdx.x, wave = tid >> 6, lane = tid & 63;
  const int r31 = lane & 31, hi = lane >> 5;
  const int head = blockIdx.x & 31, qt = blockIdx.x >> 5;
  const long hrow = (long)head * SLEN;
  const int qrow0 = qt * 128 + wave * 32;

  // block-local reduce of kpart (identical result to a global reduce)
  float km = 0.f;
  for (int i = tid; i < 2048; i += 256) km = fmaxf(km, kpart[i]);
#pragma unroll
  for (int m = 1; m <= 32; m <<= 1) km = fmaxf(km, __shfl_xor(km, m, 64));
  if (lane == 0) sm[wave] = km;
  __syncthreads();
  const float xmax = fmaxf(fmaxf(sm[0], sm[1]), fmaxf(sm[2], sm[3])) + 1e-8f;
  const float Bk = 11.313708499f * ((3.5f + qjl[0] * xmax) * xmax / 3.5f) * 1.02f * 0.5f;

  // Q fragments, B-layout of 32x32x16 (pre-scaled by log2e/sqrt(128))
  bf16x8 qf[8];
#pragma unroll
  for (int t = 0; t < 8; ++t)
    qf[t] = *(const bf16x8*)&qb[(hrow + qrow0 + r31) * DH + t * 16 + hi * 8];
  const float mqneg = -(qn[hrow + qrow0 + r31] * Bk);   // log2-domain bound

  // Ks LDS read byte-offsets (tile-invariant): chunk (2t+hi) XOR (row&7)
  int koff[8];
#pragma unroll
  for (int t = 0; t < 8; ++t)
    koff[t] = r31 * 256 + (((2 * t + hi) ^ (r31 & 7)) << 4);

  // V LDS read base, u64 units: 16B unit (half,hi,dt,r31) at u64 idx
  // half*512 + hi*256 + dt*64 + 2*r31  (round-6-verified)
  const int vbse = hi * 256 + 2 * r31;

  // K DMA source (swizzle-compensated) / dest
  const __bf16* ksrc[2]; int kds[2];
#pragma unroll
  for (int u = 0; u < 2; ++u) {
    int c = (wave * 2 + u) * 64 + lane;
    int row = c >> 4, ch = (c & 15) ^ (row & 7);
    ksrc[u] = kd + (hrow + row) * DH + ch * 8;
    kds[u] = (wave * 2 + u) * 512;
  }
  // V DMA source: linear copy of the per-tile 8KB block
  const char* vbase = (const char*)(vdt2 + (long)head * 64 * 1024);
  const char* vsrc[2];
#pragma unroll
  for (int u = 0; u < 2; ++u)
    vsrc[u] = vbase + (long)((wave * 2 + u) * 64 + lane) * 16;

  // stage tile T into buffer B: 4 DMAs/thread (K 8KB + V 8KB)
  auto STAGE = [&](int B, int T) {
    const long ko = (long)T * 32 * DH;   // bf16 elements
    const long vo = (long)T * 8192;      // bytes
    lds_dma16(ksrc[0] + ko, &Ks[B][kds[0]]);
    lds_dma16(ksrc[1] + ko, &Ks[B][kds[1]]);
    lds_dma16(vsrc[0] + vo, &Vt[B][(wave * 2 + 0) * 128]);
    lds_dma16(vsrc[1] + vo, &Vt[B][(wave * 2 + 1) * 128]);
  };

  STAGE(0, 0);

  f32x16 acc[4];
#pragma unroll
  for (int dt = 0; dt < 4; ++dt) acc[dt] = zero16();
  float ls0 = 0.f, ls1 = 0.f, ls2 = 0.f, ls3 = 0.f;

#pragma unroll 2
  for (int t = 0; t < 64; ++t) {
    const int B = t & 1;
    asm volatile("s_waitcnt vmcnt(0)" ::: "memory");   // own DMAs for tile t landed
    __builtin_amdgcn_s_barrier();                      // => all waves' DMAs landed
    asm volatile("" ::: "memory");
    if (t < 63) STAGE(B ^ 1, t + 1);                   // flight = this compute phase

    // S^T = K Q^T: single 8-MFMA chain, s starts at -Mq
    f32x16 s;
#pragma unroll
    for (int r = 0; r < 16; ++r) s[r] = mqneg;
    const char* kb = (const char*)&Ks[B][0];
    __builtin_amdgcn_s_setprio(1);
#pragma unroll
    for (int tt = 0; tt < 8; ++tt) {
      bf16x8 ka = *(const bf16x8*)(kb + koff[tt]);
      s = mfma_bf16_32x32x16(ka, qf[tt], s);
    }
    __builtin_amdgcn_s_setprio(0);

    // softmax numerator, P in registers
    float p[16];
#pragma unroll
    for (int r = 0; r < 16; ++r) p[r] = __builtin_amdgcn_exp2f(s[r]);
#pragma unroll
    for (int r = 0; r < 16; r += 4) {
      ls0 += p[r]; ls1 += p[r + 1]; ls2 += p[r + 2]; ls3 += p[r + 3];
    }
    bf16x8 pa, pb;
#pragma unroll
    for (int jj = 0; jj < 8; ++jj) { pa[jj] = (__bf16)p[jj]; pb[jj] = (__bf16)p[8 + jj]; }

    // PV: O[q][d] += P V  (x16, B-fragments from permuted V tile)
    const u64* vb = &Vt[B][0] + vbse;
    __builtin_amdgcn_s_setprio(1);
#pragma unroll
    for (int dt = 0; dt < 4; ++dt)
      acc[dt] = mfma_bf16_32x32x16(pa, *(const bf16x8*)(vb + dt * 64), acc[dt]);
#pragma unroll
    for (int dt = 0; dt < 4; ++dt)
      acc[dt] = mfma_bf16_32x32x16(pb, *(const bf16x8*)(vb + 512 + dt * 64), acc[dt]);
    __builtin_amdgcn_s_setprio(0);
  }

  float lsum = (ls0 + ls1) + (ls2 + ls3);
  lsum += __shfl_xor(lsum, 32, 64);
  if (hi == 0) Ls[wave][r31] = 1.0f / lsum;
  __syncthreads();

#pragma unroll
  for (int dt = 0; dt < 4; ++dt)
#pragma unroll
    for (int r = 0; r < 16; ++r) {
      int qr = (r & 3) + 8 * (r >> 2) + 4 * hi;
      orot[(hrow + qrow0 + qr) * DH + dt * 32 + r31] =
          (_Float16)(acc[dt][r] * Ls[wave][qr]);
    }
}

// ---------------------------------------------------------------------------
extern "C" void kernel_launch(void* const* d_in, const int* in_sizes, int n_in,
                              void* d_out, int out_size, void* d_ws, size_t ws_size,
                              hipStream_t stream)
{
  const float* q   = (const float*)d_in[0];
  const float* k   = (const float*)d_in[1];
  const float* v   = (const float*)d_in[2];
  const float* R   = (const float*)d_in[3];
  const float* qjl = (const float*)d_in[4];

  char* ws = (char*)d_ws;
  float* kpart = (float*)ws;                      // [2048]
  float* vpart = (float*)(ws + 8192);             // [2048]
  _Float16* Bhi  = (_Float16*)(ws + 32768);       // R row-major f16 hi (32KB)
  _Float16* Blo  = (_Float16*)(ws + 65536);
  _Float16* BhiT = (_Float16*)(ws + 98304);       // R^T f16 hi
  _Float16* BloT = (_Float16*)(ws + 131072);
  float* qn = (float*)(ws + 163840);              // [65536] (256KB)
  char* base = ws + 425984;
  __bf16* qb   = (__bf16*)base;                                 // 16 MiB
  float*  kr   = (float*)(base + (16u << 20));                  // 32 MiB
  float*  vr   = (float*)(base + (48u << 20));                  // 32 MiB
  u64*    vdt2 = (u64*)(base + (80u << 20));                    // 16 MiB
  __bf16* kd   = (__bf16*)vr;       // reuse vr after quantize_vt consumed it
  _Float16* orot = (_Float16*)kr;   // reuse kr after quantize_k consumed it

  dim3 b256(256);
  prep_R<<<64, b256, 0, stream>>>(R, Bhi, Blo, BhiT, BloT);
  rot_kv_kernel<<<1024, b256, 0, stream>>>(k, v, BhiT, BloT, kr, vr, kpart, vpart);
  rot_q_kernel<<<512, b256, 0, stream>>>(q, BhiT, BloT, qb, qn);
  quantize_vt_kernel<<<2048, b256, 0, stream>>>(vr, vpart, qjl, vdt2);
  quantize_k_kernel<<<8192, b256, 0, stream>>>(kr, kpart, qjl, kd);
  attn2<<<512, b256, 0, stream>>>(qb, kd, vdt2, qn, kpart, qjl, orot);
  rot_o_kernel<<<512, b256, 0, stream>>>(orot, Bhi, (float*)d_out);
}

// Round 11
// 274.398 us; speedup vs baseline: 1.9067x; 1.5028x over previous
//
#include <hip/hip_runtime.h>

// ---------------------------------------------------------------------------
// TurboQuantAttention — round 13 (= round 12 resubmitted after infra failure).
// attn2 = the verified 79-us pair-pipelined kernel (round 2/4), VERBATIM
// except the epilogue stores orot as f16 (read path validated in round 9).
// rot_kv + rot_q merged into rot_all (grid 1536) with a 32KB-LDS restage
// for the NT3 hi/lo rotation: stage R_hi -> (ah*BH + al*BH) -> barrier ->
// restage R_lo into the same buffer -> (+ ah*BL). Same 3 MFMA terms; LDS
// 64->32KB doubles occupancy (4 blocks/CU, 4 waves/SIMD, grid supplies it).
// rot_o reads f16. Launches 7 -> 6.
// ---------------------------------------------------------------------------

typedef float    f32x4  __attribute__((ext_vector_type(4)));
typedef float    f32x16 __attribute__((ext_vector_type(16)));
typedef __bf16   bf16x8 __attribute__((ext_vector_type(8)));
typedef __bf16   bf16x4 __attribute__((ext_vector_type(4)));
typedef _Float16 f16x8  __attribute__((ext_vector_type(8)));
typedef unsigned long long u64;

#define SLEN 2048
#define DH   128

static __device__ __forceinline__ f32x16 zero16() {
  f32x16 z;
#pragma unroll
  for (int i = 0; i < 16; ++i) z[i] = 0.f;
  return z;
}

static __device__ __forceinline__ f32x16 mfma_bf16_32x32x16(bf16x8 a, bf16x8 b, f32x16 c) {
  return __builtin_amdgcn_mfma_f32_32x32x16_bf16(a, b, c, 0, 0, 0);
}
static __device__ __forceinline__ f32x16 mfma_f16_32x32x16(f16x8 a, f16x8 b, f32x16 c) {
  return __builtin_amdgcn_mfma_f32_32x32x16_f16(a, b, c, 0, 0, 0);
}

// async global->LDS, 16B per lane; lds base is wave-uniform, lane i lands at +i*16
static __device__ __forceinline__ void lds_dma16(const void* g, void* l) {
  __builtin_amdgcn_global_load_lds(
      (const __attribute__((address_space(1))) void*)(unsigned long long)g,
      (__attribute__((address_space(3))) void*)(unsigned int)(unsigned long long)l,
      16, 0, 0);
}

// quantize->dequantize one element, op-order identical to reference (fp32)
static __device__ __forceinline__ float qdq(float xr, float xmax, float qs) {
  float xs = xr / xmax * 3.5f;
  float xq = rintf(xs * 4.0f) * 0.25f;
  xq = fminf(3.5f, fmaxf(-3.5f, xq));
  float res = xs - xq;
  float sg = (res > 0.0f) ? 1.0f : ((res < 0.0f) ? -1.0f : 0.0f);
  float xc = xq + sg * qs * xmax;
  return xc / 3.5f * xmax;
}

static __device__ __forceinline__ unsigned short bfbits(float f) {
  __bf16 b = (__bf16)f;
  return __builtin_bit_cast(unsigned short, b);
}

// ---------------------------------------------------------------------------
// prep_R: split R (fp32 128x128) into f16 hi/lo, row-major and transposed.
// ---------------------------------------------------------------------------
__global__ __launch_bounds__(256) void prep_R(
    const float* __restrict__ R, _Float16* __restrict__ Bhi,
    _Float16* __restrict__ Blo, _Float16* __restrict__ BhiT,
    _Float16* __restrict__ BloT)
{
  int i = blockIdx.x * 256 + threadIdx.x;   // 0..16383
  int kk = i >> 7, n = i & 127;
  float r = R[i];
  _Float16 h = (_Float16)r;
  _Float16 l = (_Float16)(r - (float)h);
  Bhi[i] = h; Blo[i] = l;
  BhiT[n * 128 + kk] = h; BloT[n * 128 + kk] = l;
}

// ---------------------------------------------------------------------------
// rot_all: one launch, grid 1536.
//  blocks 0..511:    kr = k @ R^T (3-term, restaged)  + kpart absmax
//  blocks 512..1023: vr = v @ R^T (3-term, restaged)  + vpart absmax
//  blocks 1024..1535: qb = bf16(q @ R^T * log2e/sqrt(128)) + qn row norms
// All paths use one 32KB LDS buffer -> 4 blocks/CU.
// ---------------------------------------------------------------------------
__global__ __launch_bounds__(256) void rot_all_kernel(
    const float* __restrict__ K, const float* __restrict__ V,
    const float* __restrict__ Q, const _Float16* __restrict__ Gh,
    const _Float16* __restrict__ Gl, float* __restrict__ kr,
    float* __restrict__ vr, float* __restrict__ kpart,
    float* __restrict__ vpart, __bf16* __restrict__ qb,
    float* __restrict__ qn)
{
  __shared__ _Float16 BH[128 * 128];

  const int tid = threadIdx.x, wave = tid >> 6, lane = tid & 63;
  const int r31 = lane & 31, hi = lane >> 5;
  const int bid = blockIdx.x;

  // BH staging pattern (XOR-swizzled 16B chunks), reused for hi and lo
  int stage_n[8], stage_ch[8], stage_dst[8];
#pragma unroll
  for (int u = 0; u < 8; ++u) {
    int c = (wave * 8 + u) * 64 + lane;
    stage_n[u] = c >> 4;
    stage_ch[u] = (c & 15) ^ (stage_n[u] & 7);
    stage_dst[u] = (wave * 8 + u) * 512;
  }

  if (bid < 1024) {
    // ---------------- k/v path: 3-term with restage, MODE0 ----------------
    const bool isv = bid >= 512;
    const int b = bid & 511;
    const float* X = isv ? V : K;
    float* OUT = isv ? vr : kr;
    float* part = isv ? vpart : kpart;
    const long r0 = (long)b * 128;

#pragma unroll
    for (int u = 0; u < 8; ++u)
      lds_dma16(Gh + stage_n[u] * 128 + stage_ch[u] * 8, BH + stage_dst[u]);

    const long rowg = r0 + wave * 32 + r31;
    f16x8 ah[8], al[8];
#pragma unroll
    for (int t = 0; t < 8; ++t) {
      f32x4 x0 = *(const f32x4*)&X[rowg * 128 + t * 16 + hi * 8];
      f32x4 x1 = *(const f32x4*)&X[rowg * 128 + t * 16 + hi * 8 + 4];
#pragma unroll
      for (int j = 0; j < 4; ++j) {
        _Float16 h0 = (_Float16)x0[j]; ah[t][j] = h0;
        _Float16 h1 = (_Float16)x1[j]; ah[t][4 + j] = h1;
        al[t][j]     = (_Float16)(x0[j] - (float)h0);
        al[t][4 + j] = (_Float16)(x1[j] - (float)h1);
      }
    }
    __syncthreads();

    f32x16 acc[4];
#pragma unroll
    for (int ct = 0; ct < 4; ++ct) acc[ct] = zero16();
#pragma unroll
    for (int ct = 0; ct < 4; ++ct) {
#pragma unroll
      for (int t = 0; t < 8; ++t) {
        int idx = (ct * 32 + r31) * 128 + (((2 * t + hi) ^ (r31 & 7)) * 8);
        f16x8 bh = *(const f16x8*)&BH[idx];
        acc[ct] = mfma_f16_32x32x16(ah[t], bh, acc[ct]);
        acc[ct] = mfma_f16_32x32x16(al[t], bh, acc[ct]);
      }
    }

    __syncthreads();   // all reads of BH(hi) complete
#pragma unroll
    for (int u = 0; u < 8; ++u)
      lds_dma16(Gl + stage_n[u] * 128 + stage_ch[u] * 8, BH + stage_dst[u]);
    __syncthreads();   // drains own DMAs (vmcnt 0) + barrier => BH = lo

#pragma unroll
    for (int ct = 0; ct < 4; ++ct) {
#pragma unroll
      for (int t = 0; t < 8; ++t) {
        int idx = (ct * 32 + r31) * 128 + (((2 * t + hi) ^ (r31 & 7)) * 8);
        f16x8 bl = *(const f16x8*)&BH[idx];
        acc[ct] = mfma_f16_32x32x16(ah[t], bl, acc[ct]);
      }
    }

    float am = 0.f;
#pragma unroll
    for (int ct = 0; ct < 4; ++ct)
#pragma unroll
      for (int r = 0; r < 16; ++r) {
        long grow = r0 + wave * 32 + (r & 3) + 8 * (r >> 2) + 4 * hi;
        float v = acc[ct][r];
        OUT[grow * 128 + ct * 32 + r31] = v;
        am = fmaxf(am, fabsf(v));
      }
#pragma unroll
    for (int m = 1; m <= 32; m <<= 1) am = fmaxf(am, __shfl_xor(am, m, 64));
    if (lane == 0) part[b * 4 + wave] = am;

  } else {
    // ---------------- q path: single-pass f16, MODE1 ----------------
    const int b = bid - 1024;
    const long r0 = (long)b * 128;

#pragma unroll
    for (int u = 0; u < 8; ++u)
      lds_dma16(Gh + stage_n[u] * 128 + stage_ch[u] * 8, BH + stage_dst[u]);

    const long rowg = r0 + wave * 32 + r31;
    f16x8 ah[8];
#pragma unroll
    for (int t = 0; t < 8; ++t) {
      f32x4 x0 = *(const f32x4*)&Q[rowg * 128 + t * 16 + hi * 8];
      f32x4 x1 = *(const f32x4*)&Q[rowg * 128 + t * 16 + hi * 8 + 4];
#pragma unroll
      for (int j = 0; j < 4; ++j) {
        ah[t][j]     = (_Float16)x0[j];
        ah[t][4 + j] = (_Float16)x1[j];
      }
    }
    __syncthreads();

    f32x16 acc[4];
#pragma unroll
    for (int ct = 0; ct < 4; ++ct) acc[ct] = zero16();
#pragma unroll
    for (int ct = 0; ct < 4; ++ct) {
#pragma unroll
      for (int t = 0; t < 8; ++t) {
        int idx = (ct * 32 + r31) * 128 + (((2 * t + hi) ^ (r31 & 7)) * 8);
        f16x8 bh = *(const f16x8*)&BH[idx];
        acc[ct] = mfma_f16_32x32x16(ah[t], bh, acc[ct]);
      }
    }

    const float sc = 0.12751743342f;   // log2(e)/sqrt(128): exp2-domain scores
    float rs[16];
#pragma unroll
    for (int r = 0; r < 16; ++r) rs[r] = 0.f;
#pragma unroll
    for (int ct = 0; ct < 4; ++ct)
#pragma unroll
      for (int r = 0; r < 16; ++r) {
        long grow = r0 + wave * 32 + (r & 3) + 8 * (r >> 2) + 4 * hi;
        __bf16 bb = (__bf16)(acc[ct][r] * sc);
        qb[grow * 128 + ct * 32 + r31] = bb;
        float fb = (float)bb;
        rs[r] += fb * fb;
      }
#pragma unroll
    for (int r = 0; r < 16; ++r) {
#pragma unroll
      for (int msk = 1; msk <= 16; msk <<= 1) rs[r] += __shfl_xor(rs[r], msk, 64);
      if (r31 == r)
        qn[r0 + wave * 32 + (r & 3) + 8 * (r >> 2) + 4 * hi] = sqrtf(rs[r]);
    }
  }
}

// ---------------------------------------------------------------------------
// rot_o: y = x @ R from f16 input (validated in round 9).
// ---------------------------------------------------------------------------
__global__ __launch_bounds__(256) void rot_o_kernel(
    const _Float16* __restrict__ X, const _Float16* __restrict__ Gh,
    float* __restrict__ OUT)
{
  __shared__ _Float16 BH[128 * 128];

  const int tid = threadIdx.x, wave = tid >> 6, lane = tid & 63;
  const int r31 = lane & 31, hi = lane >> 5;
  const long r0 = (long)blockIdx.x * 128;

#pragma unroll
  for (int u = 0; u < 8; ++u) {
    int c = (wave * 8 + u) * 64 + lane;
    int n = c >> 4, p = c & 15, ch = p ^ (n & 7);
    lds_dma16(Gh + n * 128 + ch * 8, BH + (wave * 8 + u) * 512);
  }

  const long rowg = r0 + wave * 32 + r31;
  f16x8 ah[8];
#pragma unroll
  for (int t = 0; t < 8; ++t)
    ah[t] = *(const f16x8*)&X[rowg * 128 + t * 16 + hi * 8];
  __syncthreads();

  f32x16 acc[4];
#pragma unroll
  for (int ct = 0; ct < 4; ++ct) acc[ct] = zero16();
#pragma unroll
  for (int ct = 0; ct < 4; ++ct) {
#pragma unroll
    for (int t = 0; t < 8; ++t) {
      int idx = (ct * 32 + r31) * 128 + (((2 * t + hi) ^ (r31 & 7)) * 8);
      f16x8 bh = *(const f16x8*)&BH[idx];
      acc[ct] = mfma_f16_32x32x16(ah[t], bh, acc[ct]);
    }
  }
#pragma unroll
  for (int ct = 0; ct < 4; ++ct)
#pragma unroll
    for (int r = 0; r < 16; ++r) {
      long grow = r0 + wave * 32 + (r & 3) + 8 * (r >> 2) + 4 * hi;
      OUT[grow * 128 + ct * 32 + r31] = acc[ct][r];
    }
}

// ---------------------------------------------------------------------------
// quantize+dequant v -> per-tile x16 B-fragment layout (verified):
//   per 32-key tile (8KB): 16B unit u = (half*2+hi)*128 + d holds keys
//   {16*half+4*hi+(0..3), 16*half+4*hi+8+(0..3)} at row d.
// ---------------------------------------------------------------------------
__global__ __launch_bounds__(256) void quantize_vt_kernel(
    const float* __restrict__ vr, const float* __restrict__ vpart,
    const float* __restrict__ qjl, u64* __restrict__ vdt2)
{
  __shared__ unsigned int Ts32[128][18];
  __shared__ float sm[4];
  const int tid = threadIdx.x;

  float m = 0.f;
  for (int i = tid; i < 2048; i += 256) m = fmaxf(m, vpart[i]);
#pragma unroll
  for (int msk = 1; msk <= 32; msk <<= 1) m = fmaxf(m, __shfl_xor(m, msk, 64));
  if ((tid & 63) == 0) sm[tid >> 6] = m;
  __syncthreads();
  const float xmax = fmaxf(fmaxf(sm[0], sm[1]), fmaxf(sm[2], sm[3])) + 1e-8f;
  const float qs = qjl[0];

  const int bh = blockIdx.x >> 6, blk = blockIdx.x & 63;
  const int s0 = blk * 32;
  const int sp  = tid & 15;
  const int dch = tid >> 4;
  const long rb = (long)bh * SLEN + s0;
  const float* p0 = &vr[(rb + sp * 2    ) * 128 + dch * 8];
  const float* p1 = &vr[(rb + sp * 2 + 1) * 128 + dch * 8];
#pragma unroll
  for (int j = 0; j < 8; ++j) {
    unsigned a = bfbits(qdq(p0[j], xmax, qs));
    unsigned b = bfbits(qdq(p1[j], xmax, qs));
    Ts32[dch * 8 + j][sp] = a | (b << 16);   // keys (s0+2sp, s0+2sp+1), row dch*8+j
  }
  __syncthreads();
  const long obase = (long)(bh * 64 + blk) * 1024;   // u64 units per tile
#pragma unroll
  for (int uu = 0; uu < 2; ++uu) {
    int u_ = uu * 256 + tid;                 // 0..511: (half,hi,d)
    int half = u_ >> 8, hi = (u_ >> 7) & 1, d = u_ & 127;
    u64 qlo = *(const u64*)&Ts32[d][2 * (half * 4 + hi)];
    u64 qhi = *(const u64*)&Ts32[d][2 * (half * 4 + hi + 2)];
    vdt2[obase + u_ * 2    ] = qlo;
    vdt2[obase + u_ * 2 + 1] = qhi;
  }
}

// elementwise quantize+dequant k -> bf16 natural layout (+ inline kmax reduce)
__global__ __launch_bounds__(256) void quantize_k_kernel(
    const float* __restrict__ kr, const float* __restrict__ kpart,
    const float* __restrict__ qjl, __bf16* __restrict__ out)
{
  __shared__ float sm[4];
  const int tid = threadIdx.x;
  float m = 0.f;
  for (int i = tid; i < 2048; i += 256) m = fmaxf(m, kpart[i]);
#pragma unroll
  for (int msk = 1; msk <= 32; msk <<= 1) m = fmaxf(m, __shfl_xor(m, msk, 64));
  if ((tid & 63) == 0) sm[tid >> 6] = m;
  __syncthreads();
  const float xmax = fmaxf(fmaxf(sm[0], sm[1]), fmaxf(sm[2], sm[3])) + 1e-8f;
  const float qs = qjl[0];

  long i = ((long)blockIdx.x * 256 + tid) * 4;
  f32x4 x = *(const f32x4*)&kr[i];
  bf16x4 ov;
#pragma unroll
  for (int j = 0; j < 4; ++j) ov[j] = (__bf16)qdq(x[j], xmax, qs);
  *(bf16x4*)&out[i] = ov;
}

// ---------------------------------------------------------------------------
// attn2: flash attention, pair-pipelined — the verified 79-us kernel.
// Only change: orot stored as f16 (read path validated in round 9).
// ---------------------------------------------------------------------------
__global__ __launch_bounds__(256, 2) void attn2(
    const __bf16* __restrict__ qb, const __bf16* __restrict__ kd,
    const u64* __restrict__ vdt2, const float* __restrict__ qn,
    const float* __restrict__ kpart, const float* __restrict__ qjl,
    _Float16* __restrict__ orot)
{
  __shared__ __attribute__((aligned(16))) __bf16 Ks[2][2][32 * DH]; // 32KB
  __shared__ __attribute__((aligned(16))) u64   Vt[2][2][1024];     // 32KB
  __shared__ float Ls[4][32];
  __shared__ float sm[4];

  const int tid = threadIdx.x, wave = tid >> 6, lane = tid & 63;
  const int r31 = lane & 31, hi = lane >> 5;
  const int head = blockIdx.x & 31, qt = blockIdx.x >> 5;
  const long hrow = (long)head * SLEN;
  const int qrow0 = qt * 128 + wave * 32;

  // block-local reduce of kpart (identical result to a global reduce)
  float km = 0.f;
  for (int i = tid; i < 2048; i += 256) km = fmaxf(km, kpart[i]);
#pragma unroll
  for (int m = 1; m <= 32; m <<= 1) km = fmaxf(km, __shfl_xor(km, m, 64));
  if (lane == 0) sm[wave] = km;
  __syncthreads();
  const float xmax = fmaxf(fmaxf(sm[0], sm[1]), fmaxf(sm[2], sm[3])) + 1e-8f;
  const float Bk = 11.313708499f * ((3.5f + qjl[0] * xmax) * xmax / 3.5f) * 1.02f * 0.5f;

  // Q fragments, B-layout of 32x32x16 (pre-scaled by log2e/sqrt(128))
  bf16x8 qf[8];
#pragma unroll
  for (int t = 0; t < 8; ++t)
    qf[t] = *(const bf16x8*)&qb[(hrow + qrow0 + r31) * DH + t * 16 + hi * 8];
  const float mqneg = -(qn[hrow + qrow0 + r31] * Bk);   // log2-domain bound

  // Ks LDS read byte-offsets (tile-invariant): chunk (2t+hi) XOR (row&7)
  int koff[8];
#pragma unroll
  for (int t = 0; t < 8; ++t)
    koff[t] = r31 * 256 + (((2 * t + hi) ^ (r31 & 7)) << 4);

  // V LDS read byte-offsets per (half, dt)
  int vof0[4], vof1[4];
#pragma unroll
  for (int dt = 0; dt < 4; ++dt) {
    vof0[dt] = (((0 * 2 + hi) * 128) + dt * 32 + r31) * 16;
    vof1[dt] = (((1 * 2 + hi) * 128) + dt * 32 + r31) * 16;
  }

  // K DMA source (swizzle-compensated) / dest
  const __bf16* ksrc[2]; int kds[2];
#pragma unroll
  for (int u = 0; u < 2; ++u) {
    int c = (wave * 2 + u) * 64 + lane;
    int row = c >> 4, ch = (c & 15) ^ (row & 7);
    ksrc[u] = kd + (hrow + row) * DH + ch * 8;
    kds[u] = (wave * 2 + u) * 512;
  }
  // V DMA source: linear copy of the per-tile 8KB block
  const char* vbase = (const char*)(vdt2 + (long)head * 64 * 1024);
  const char* vsrc[2];
#pragma unroll
  for (int u = 0; u < 2; ++u)
    vsrc[u] = vbase + (long)((wave * 2 + u) * 64 + lane) * 16;

  // stage pair P (tiles 2P, 2P+1) into buffer B: 8 DMAs/thread
  auto STAGE = [&](int B, int P) {
    const long k0 = (long)(2 * P) * 32 * DH, k1 = k0 + 32 * DH;
    const long v0 = (long)(2 * P) * 8192,    v1 = v0 + 8192;
    lds_dma16(ksrc[0] + k0, &Ks[B][0][kds[0]]);
    lds_dma16(ksrc[1] + k0, &Ks[B][0][kds[1]]);
    lds_dma16(ksrc[0] + k1, &Ks[B][1][kds[0]]);
    lds_dma16(ksrc[1] + k1, &Ks[B][1][kds[1]]);
    lds_dma16(vsrc[0] + v0, &Vt[B][0][(wave * 2 + 0) * 128]);
    lds_dma16(vsrc[1] + v0, &Vt[B][0][(wave * 2 + 1) * 128]);
    lds_dma16(vsrc[0] + v1, &Vt[B][1][(wave * 2 + 0) * 128]);
    lds_dma16(vsrc[1] + v1, &Vt[B][1][(wave * 2 + 1) * 128]);
  };

  // prologue: stage pairs 0 and 1; wait pair 0 only
  STAGE(0, 0);
  STAGE(1, 1);
  asm volatile("s_waitcnt vmcnt(8)" ::: "memory");
  __builtin_amdgcn_s_barrier();
  asm volatile("" ::: "memory");

  f32x16 acc[4];
#pragma unroll
  for (int dt = 0; dt < 4; ++dt) acc[dt] = zero16();
  float ls0 = 0.f, ls1 = 0.f, ls2 = 0.f, ls3 = 0.f;

  // softmax + PV for one tile (P fragments feed x16 PV directly)
  auto TILE = [&](const f32x16& sa, const f32x16& sb, int B, int j) {
    float p[16];
#pragma unroll
    for (int r = 0; r < 16; ++r) p[r] = __builtin_amdgcn_exp2f(sa[r] + sb[r]);
#pragma unroll
    for (int r = 0; r < 16; r += 4) {
      ls0 += p[r]; ls1 += p[r + 1]; ls2 += p[r + 2]; ls3 += p[r + 3];
    }
    bf16x8 pa, pb;
#pragma unroll
    for (int jj = 0; jj < 8; ++jj) { pa[jj] = (__bf16)p[jj]; pb[jj] = (__bf16)p[8 + jj]; }
    const char* vb = (const char*)&Vt[B][j][0];
    __builtin_amdgcn_s_setprio(1);
#pragma unroll
    for (int dt = 0; dt < 4; ++dt) {
      bf16x8 v0 = *(const bf16x8*)(vb + vof0[dt]);
      acc[dt] = mfma_bf16_32x32x16(pa, v0, acc[dt]);
    }
#pragma unroll
    for (int dt = 0; dt < 4; ++dt) {
      bf16x8 v1 = *(const bf16x8*)(vb + vof1[dt]);
      acc[dt] = mfma_bf16_32x32x16(pb, v1, acc[dt]);
    }
    __builtin_amdgcn_s_setprio(0);
  };

#pragma unroll 1
  for (int i = 0; i < SLEN / 64; ++i) {
    const int B = i & 1;
    const char* k0 = (const char*)&Ks[B][0][0];
    const char* k1 = (const char*)&Ks[B][1][0];

    // S^T = K Q^T, 4 interleaved chains; sb accumulators start at -Mq
    f32x16 sa0 = zero16(), sa1 = zero16(), sb0, sb1;
#pragma unroll
    for (int r = 0; r < 16; ++r) { sb0[r] = mqneg; sb1[r] = mqneg; }
    __builtin_amdgcn_s_setprio(1);
#pragma unroll
    for (int t = 0; t < 8; t += 2) {
      bf16x8 ka0 = *(const bf16x8*)(k0 + koff[t]);
      bf16x8 kb0 = *(const bf16x8*)(k1 + koff[t]);
      bf16x8 ka1 = *(const bf16x8*)(k0 + koff[t + 1]);
      bf16x8 kb1 = *(const bf16x8*)(k1 + koff[t + 1]);
      sa0 = mfma_bf16_32x32x16(ka0, qf[t], sa0);
      sa1 = mfma_bf16_32x32x16(kb0, qf[t], sa1);
      sb0 = mfma_bf16_32x32x16(ka1, qf[t + 1], sb0);
      sb1 = mfma_bf16_32x32x16(kb1, qf[t + 1], sb1);
    }
    __builtin_amdgcn_s_setprio(0);

    TILE(sa0, sb0, B, 0);
    TILE(sa1, sb1, B, 1);

    if (i < SLEN / 64 - 1) {
      asm volatile("s_waitcnt vmcnt(0)" ::: "memory");   // pair i+1 landed
      __builtin_amdgcn_s_barrier();                      // raw: no drain
      asm volatile("" ::: "memory");
      if (i < SLEN / 64 - 2) STAGE(B, i + 2);
    }
  }

  float lsum = (ls0 + ls1) + (ls2 + ls3);
  lsum += __shfl_xor(lsum, 32, 64);
  if (hi == 0) Ls[wave][r31] = 1.0f / lsum;
  __syncthreads();

#pragma unroll
  for (int dt = 0; dt < 4; ++dt)
#pragma unroll
    for (int r = 0; r < 16; ++r) {
      int qr = (r & 3) + 8 * (r >> 2) + 4 * hi;
      orot[(hrow + qrow0 + qr) * DH + dt * 32 + r31] =
          (_Float16)(acc[dt][r] * Ls[wave][qr]);
    }
}

// ---------------------------------------------------------------------------
extern "C" void kernel_launch(void* const* d_in, const int* in_sizes, int n_in,
                              void* d_out, int out_size, void* d_ws, size_t ws_size,
                              hipStream_t stream)
{
  const float* q   = (const float*)d_in[0];
  const float* k   = (const float*)d_in[1];
  const float* v   = (const float*)d_in[2];
  const float* R   = (const float*)d_in[3];
  const float* qjl = (const float*)d_in[4];

  char* ws = (char*)d_ws;
  float* kpart = (float*)ws;                      // [2048]
  float* vpart = (float*)(ws + 8192);             // [2048]
  _Float16* Bhi  = (_Float16*)(ws + 32768);       // R row-major f16 hi (32KB)
  _Float16* Blo  = (_Float16*)(ws + 65536);
  _Float16* BhiT = (_Float16*)(ws + 98304);       // R^T f16 hi
  _Float16* BloT = (_Float16*)(ws + 131072);
  float* qn = (float*)(ws + 163840);              // [65536] (256KB)
  char* base = ws + 425984;
  __bf16* qb   = (__bf16*)base;                                 // 16 MiB
  float*  kr   = (float*)(base + (16u << 20));                  // 32 MiB
  float*  vr   = (float*)(base + (48u << 20));                  // 32 MiB
  u64*    vdt2 = (u64*)(base + (80u << 20));                    // 16 MiB
  __bf16* kd   = (__bf16*)vr;       // reuse vr after quantize_vt consumed it
  _Float16* orot = (_Float16*)kr;   // reuse kr after quantize_k consumed it

  dim3 b256(256);
  prep_R<<<64, b256, 0, stream>>>(R, Bhi, Blo, BhiT, BloT);
  rot_all_kernel<<<1536, b256, 0, stream>>>(k, v, q, BhiT, BloT, kr, vr,
                                            kpart, vpart, qb, qn);
  quantize_vt_kernel<<<2048, b256, 0, stream>>>(vr, vpart, qjl, vdt2);
  quantize_k_kernel<<<8192, b256, 0, stream>>>(kr, kpart, qjl, kd);
  attn2<<<512, b256, 0, stream>>>(qb, kd, vdt2, qn, kpart, qjl, orot);
  rot_o_kernel<<<512, b256, 0, stream>>>(orot, Bhi, (float*)d_out);
}

// Round 12
// 261.695 us; speedup vs baseline: 1.9993x; 1.0485x over previous
//
#include <hip/hip_runtime.h>

// ---------------------------------------------------------------------------
// TurboQuantAttention — round 14.
// Base = round-13 (274 us, passed). Changes:
//  1) rot_o FUSED into attn2's epilogue: after the post-loop barrier the
//     64KB LDS is repurposed — Bhi staged into the Ks region (rot_o's DMA
//     pattern), O transposed through the Vt region as f16 with the standard
//     chunk^(row&7) swizzle (value chain bit-identical to the old f16-orot
//     store->load), 32 MFMAs/wave with rot_o's B-read/C-write addressing,
//     output written straight to d_out. Launch count 6 -> 5; 48MB of orot
//     round-trip traffic eliminated.
//  2) quantize_k grid 8192 -> 2048 (16 elems/thread): per-block kpart
//     reduce traffic cut 4x.
// ---------------------------------------------------------------------------

typedef float    f32x4  __attribute__((ext_vector_type(4)));
typedef float    f32x16 __attribute__((ext_vector_type(16)));
typedef __bf16   bf16x8 __attribute__((ext_vector_type(8)));
typedef __bf16   bf16x4 __attribute__((ext_vector_type(4)));
typedef _Float16 f16x8  __attribute__((ext_vector_type(8)));
typedef unsigned long long u64;

#define SLEN 2048
#define DH   128

static __device__ __forceinline__ f32x16 zero16() {
  f32x16 z;
#pragma unroll
  for (int i = 0; i < 16; ++i) z[i] = 0.f;
  return z;
}

static __device__ __forceinline__ f32x16 mfma_bf16_32x32x16(bf16x8 a, bf16x8 b, f32x16 c) {
  return __builtin_amdgcn_mfma_f32_32x32x16_bf16(a, b, c, 0, 0, 0);
}
static __device__ __forceinline__ f32x16 mfma_f16_32x32x16(f16x8 a, f16x8 b, f32x16 c) {
  return __builtin_amdgcn_mfma_f32_32x32x16_f16(a, b, c, 0, 0, 0);
}

// async global->LDS, 16B per lane; lds base is wave-uniform, lane i lands at +i*16
static __device__ __forceinline__ void lds_dma16(const void* g, void* l) {
  __builtin_amdgcn_global_load_lds(
      (const __attribute__((address_space(1))) void*)(unsigned long long)g,
      (__attribute__((address_space(3))) void*)(unsigned int)(unsigned long long)l,
      16, 0, 0);
}

// quantize->dequantize one element, op-order identical to reference (fp32)
static __device__ __forceinline__ float qdq(float xr, float xmax, float qs) {
  float xs = xr / xmax * 3.5f;
  float xq = rintf(xs * 4.0f) * 0.25f;
  xq = fminf(3.5f, fmaxf(-3.5f, xq));
  float res = xs - xq;
  float sg = (res > 0.0f) ? 1.0f : ((res < 0.0f) ? -1.0f : 0.0f);
  float xc = xq + sg * qs * xmax;
  return xc / 3.5f * xmax;
}

static __device__ __forceinline__ unsigned short bfbits(float f) {
  __bf16 b = (__bf16)f;
  return __builtin_bit_cast(unsigned short, b);
}

// ---------------------------------------------------------------------------
// prep_R: split R (fp32 128x128) into f16 hi/lo, row-major and transposed.
// ---------------------------------------------------------------------------
__global__ __launch_bounds__(256) void prep_R(
    const float* __restrict__ R, _Float16* __restrict__ Bhi,
    _Float16* __restrict__ Blo, _Float16* __restrict__ BhiT,
    _Float16* __restrict__ BloT)
{
  int i = blockIdx.x * 256 + threadIdx.x;   // 0..16383
  int kk = i >> 7, n = i & 127;
  float r = R[i];
  _Float16 h = (_Float16)r;
  _Float16 l = (_Float16)(r - (float)h);
  Bhi[i] = h; Blo[i] = l;
  BhiT[n * 128 + kk] = h; BloT[n * 128 + kk] = l;
}

// ---------------------------------------------------------------------------
// rot_all: one launch, grid 1536.
//  blocks 0..511:    kr = k @ R^T (3-term, restaged)  + kpart absmax
//  blocks 512..1023: vr = v @ R^T (3-term, restaged)  + vpart absmax
//  blocks 1024..1535: qb = bf16(q @ R^T * log2e/sqrt(128)) + qn row norms
// All paths use one 32KB LDS buffer -> 4 blocks/CU.
// ---------------------------------------------------------------------------
__global__ __launch_bounds__(256) void rot_all_kernel(
    const float* __restrict__ K, const float* __restrict__ V,
    const float* __restrict__ Q, const _Float16* __restrict__ Gh,
    const _Float16* __restrict__ Gl, float* __restrict__ kr,
    float* __restrict__ vr, float* __restrict__ kpart,
    float* __restrict__ vpart, __bf16* __restrict__ qb,
    float* __restrict__ qn)
{
  __shared__ _Float16 BH[128 * 128];

  const int tid = threadIdx.x, wave = tid >> 6, lane = tid & 63;
  const int r31 = lane & 31, hi = lane >> 5;
  const int bid = blockIdx.x;

  // BH staging pattern (XOR-swizzled 16B chunks), reused for hi and lo
  int stage_n[8], stage_ch[8], stage_dst[8];
#pragma unroll
  for (int u = 0; u < 8; ++u) {
    int c = (wave * 8 + u) * 64 + lane;
    stage_n[u] = c >> 4;
    stage_ch[u] = (c & 15) ^ (stage_n[u] & 7);
    stage_dst[u] = (wave * 8 + u) * 512;
  }

  if (bid < 1024) {
    // ---------------- k/v path: 3-term with restage, MODE0 ----------------
    const bool isv = bid >= 512;
    const int b = bid & 511;
    const float* X = isv ? V : K;
    float* OUT = isv ? vr : kr;
    float* part = isv ? vpart : kpart;
    const long r0 = (long)b * 128;

#pragma unroll
    for (int u = 0; u < 8; ++u)
      lds_dma16(Gh + stage_n[u] * 128 + stage_ch[u] * 8, BH + stage_dst[u]);

    const long rowg = r0 + wave * 32 + r31;
    f16x8 ah[8], al[8];
#pragma unroll
    for (int t = 0; t < 8; ++t) {
      f32x4 x0 = *(const f32x4*)&X[rowg * 128 + t * 16 + hi * 8];
      f32x4 x1 = *(const f32x4*)&X[rowg * 128 + t * 16 + hi * 8 + 4];
#pragma unroll
      for (int j = 0; j < 4; ++j) {
        _Float16 h0 = (_Float16)x0[j]; ah[t][j] = h0;
        _Float16 h1 = (_Float16)x1[j]; ah[t][4 + j] = h1;
        al[t][j]     = (_Float16)(x0[j] - (float)h0);
        al[t][4 + j] = (_Float16)(x1[j] - (float)h1);
      }
    }
    __syncthreads();

    f32x16 acc[4];
#pragma unroll
    for (int ct = 0; ct < 4; ++ct) acc[ct] = zero16();
#pragma unroll
    for (int ct = 0; ct < 4; ++ct) {
#pragma unroll
      for (int t = 0; t < 8; ++t) {
        int idx = (ct * 32 + r31) * 128 + (((2 * t + hi) ^ (r31 & 7)) * 8);
        f16x8 bh = *(const f16x8*)&BH[idx];
        acc[ct] = mfma_f16_32x32x16(ah[t], bh, acc[ct]);
        acc[ct] = mfma_f16_32x32x16(al[t], bh, acc[ct]);
      }
    }

    __syncthreads();   // all reads of BH(hi) complete
#pragma unroll
    for (int u = 0; u < 8; ++u)
      lds_dma16(Gl + stage_n[u] * 128 + stage_ch[u] * 8, BH + stage_dst[u]);
    __syncthreads();   // drains own DMAs (vmcnt 0) + barrier => BH = lo

#pragma unroll
    for (int ct = 0; ct < 4; ++ct) {
#pragma unroll
      for (int t = 0; t < 8; ++t) {
        int idx = (ct * 32 + r31) * 128 + (((2 * t + hi) ^ (r31 & 7)) * 8);
        f16x8 bl = *(const f16x8*)&BH[idx];
        acc[ct] = mfma_f16_32x32x16(ah[t], bl, acc[ct]);
      }
    }

    float am = 0.f;
#pragma unroll
    for (int ct = 0; ct < 4; ++ct)
#pragma unroll
      for (int r = 0; r < 16; ++r) {
        long grow = r0 + wave * 32 + (r & 3) + 8 * (r >> 2) + 4 * hi;
        float v = acc[ct][r];
        OUT[grow * 128 + ct * 32 + r31] = v;
        am = fmaxf(am, fabsf(v));
      }
#pragma unroll
    for (int m = 1; m <= 32; m <<= 1) am = fmaxf(am, __shfl_xor(am, m, 64));
    if (lane == 0) part[b * 4 + wave] = am;

  } else {
    // ---------------- q path: single-pass f16, MODE1 ----------------
    const int b = bid - 1024;
    const long r0 = (long)b * 128;

#pragma unroll
    for (int u = 0; u < 8; ++u)
      lds_dma16(Gh + stage_n[u] * 128 + stage_ch[u] * 8, BH + stage_dst[u]);

    const long rowg = r0 + wave * 32 + r31;
    f16x8 ah[8];
#pragma unroll
    for (int t = 0; t < 8; ++t) {
      f32x4 x0 = *(const f32x4*)&Q[rowg * 128 + t * 16 + hi * 8];
      f32x4 x1 = *(const f32x4*)&Q[rowg * 128 + t * 16 + hi * 8 + 4];
#pragma unroll
      for (int j = 0; j < 4; ++j) {
        ah[t][j]     = (_Float16)x0[j];
        ah[t][4 + j] = (_Float16)x1[j];
      }
    }
    __syncthreads();

    f32x16 acc[4];
#pragma unroll
    for (int ct = 0; ct < 4; ++ct) acc[ct] = zero16();
#pragma unroll
    for (int ct = 0; ct < 4; ++ct) {
#pragma unroll
      for (int t = 0; t < 8; ++t) {
        int idx = (ct * 32 + r31) * 128 + (((2 * t + hi) ^ (r31 & 7)) * 8);
        f16x8 bh = *(const f16x8*)&BH[idx];
        acc[ct] = mfma_f16_32x32x16(ah[t], bh, acc[ct]);
      }
    }

    const float sc = 0.12751743342f;   // log2(e)/sqrt(128): exp2-domain scores
    float rs[16];
#pragma unroll
    for (int r = 0; r < 16; ++r) rs[r] = 0.f;
#pragma unroll
    for (int ct = 0; ct < 4; ++ct)
#pragma unroll
      for (int r = 0; r < 16; ++r) {
        long grow = r0 + wave * 32 + (r & 3) + 8 * (r >> 2) + 4 * hi;
        __bf16 bb = (__bf16)(acc[ct][r] * sc);
        qb[grow * 128 + ct * 32 + r31] = bb;
        float fb = (float)bb;
        rs[r] += fb * fb;
      }
#pragma unroll
    for (int r = 0; r < 16; ++r) {
#pragma unroll
      for (int msk = 1; msk <= 16; msk <<= 1) rs[r] += __shfl_xor(rs[r], msk, 64);
      if (r31 == r)
        qn[r0 + wave * 32 + (r & 3) + 8 * (r >> 2) + 4 * hi] = sqrtf(rs[r]);
    }
  }
}

// ---------------------------------------------------------------------------
// quantize+dequant v -> per-tile x16 B-fragment layout (verified):
//   per 32-key tile (8KB): 16B unit u = (half*2+hi)*128 + d holds keys
//   {16*half+4*hi+(0..3), 16*half+4*hi+8+(0..3)} at row d.
// ---------------------------------------------------------------------------
__global__ __launch_bounds__(256) void quantize_vt_kernel(
    const float* __restrict__ vr, const float* __restrict__ vpart,
    const float* __restrict__ qjl, u64* __restrict__ vdt2)
{
  __shared__ unsigned int Ts32[128][18];
  __shared__ float sm[4];
  const int tid = threadIdx.x;

  float m = 0.f;
  for (int i = tid; i < 2048; i += 256) m = fmaxf(m, vpart[i]);
#pragma unroll
  for (int msk = 1; msk <= 32; msk <<= 1) m = fmaxf(m, __shfl_xor(m, msk, 64));
  if ((tid & 63) == 0) sm[tid >> 6] = m;
  __syncthreads();
  const float xmax = fmaxf(fmaxf(sm[0], sm[1]), fmaxf(sm[2], sm[3])) + 1e-8f;
  const float qs = qjl[0];

  const int bh = blockIdx.x >> 6, blk = blockIdx.x & 63;
  const int s0 = blk * 32;
  const int sp  = tid & 15;
  const int dch = tid >> 4;
  const long rb = (long)bh * SLEN + s0;
  const float* p0 = &vr[(rb + sp * 2    ) * 128 + dch * 8];
  const float* p1 = &vr[(rb + sp * 2 + 1) * 128 + dch * 8];
#pragma unroll
  for (int j = 0; j < 8; ++j) {
    unsigned a = bfbits(qdq(p0[j], xmax, qs));
    unsigned b = bfbits(qdq(p1[j], xmax, qs));
    Ts32[dch * 8 + j][sp] = a | (b << 16);   // keys (s0+2sp, s0+2sp+1), row dch*8+j
  }
  __syncthreads();
  const long obase = (long)(bh * 64 + blk) * 1024;   // u64 units per tile
#pragma unroll
  for (int uu = 0; uu < 2; ++uu) {
    int u_ = uu * 256 + tid;                 // 0..511: (half,hi,d)
    int half = u_ >> 8, hi = (u_ >> 7) & 1, d = u_ & 127;
    u64 qlo = *(const u64*)&Ts32[d][2 * (half * 4 + hi)];
    u64 qhi = *(const u64*)&Ts32[d][2 * (half * 4 + hi + 2)];
    vdt2[obase + u_ * 2    ] = qlo;
    vdt2[obase + u_ * 2 + 1] = qhi;
  }
}

// elementwise quantize+dequant k -> bf16 natural layout (+ inline kmax reduce)
// grid 2048, 16 elements/thread (4x fewer redundant kpart reduces).
__global__ __launch_bounds__(256) void quantize_k_kernel(
    const float* __restrict__ kr, const float* __restrict__ kpart,
    const float* __restrict__ qjl, __bf16* __restrict__ out)
{
  __shared__ float sm[4];
  const int tid = threadIdx.x;
  float m = 0.f;
  for (int i = tid; i < 2048; i += 256) m = fmaxf(m, kpart[i]);
#pragma unroll
  for (int msk = 1; msk <= 32; msk <<= 1) m = fmaxf(m, __shfl_xor(m, msk, 64));
  if ((tid & 63) == 0) sm[tid >> 6] = m;
  __syncthreads();
  const float xmax = fmaxf(fmaxf(sm[0], sm[1]), fmaxf(sm[2], sm[3])) + 1e-8f;
  const float qs = qjl[0];

  long i = ((long)blockIdx.x * 256 + tid) * 16;
#pragma unroll
  for (int jj = 0; jj < 4; ++jj) {
    f32x4 x = *(const f32x4*)&kr[i + jj * 4];
    bf16x4 ov;
#pragma unroll
    for (int j = 0; j < 4; ++j) ov[j] = (__bf16)qdq(x[j], xmax, qs);
    *(bf16x4*)&out[i + jj * 4] = ov;
  }
}

// ---------------------------------------------------------------------------
// attn2: flash attention, pair-pipelined (verified 79-82 us) + FUSED final
// rotation. Main loop unchanged. Epilogue: normalize O, transpose to f16
// through the Vt LDS region (swizzled), stage Bhi into the Ks region, 32
// MFMAs/wave of O @ R^T (rot_o addressing), write d_out fp32 directly.
// ---------------------------------------------------------------------------
__global__ __launch_bounds__(256, 2) void attn2(
    const __bf16* __restrict__ qb, const __bf16* __restrict__ kd,
    const u64* __restrict__ vdt2, const float* __restrict__ qn,
    const float* __restrict__ kpart, const float* __restrict__ qjl,
    const _Float16* __restrict__ Bhi, float* __restrict__ OUT)
{
  __shared__ __attribute__((aligned(16))) __bf16 Ks[2][2][32 * DH]; // 32KB
  __shared__ __attribute__((aligned(16))) u64   Vt[2][2][1024];     // 32KB
  __shared__ float Ls[4][32];
  __shared__ float sm[4];

  const int tid = threadIdx.x, wave = tid >> 6, lane = tid & 63;
  const int r31 = lane & 31, hi = lane >> 5;
  const int head = blockIdx.x & 31, qt = blockIdx.x >> 5;
  const long hrow = (long)head * SLEN;
  const int qrow0 = qt * 128 + wave * 32;

  // block-local reduce of kpart (identical result to a global reduce)
  float km = 0.f;
  for (int i = tid; i < 2048; i += 256) km = fmaxf(km, kpart[i]);
#pragma unroll
  for (int m = 1; m <= 32; m <<= 1) km = fmaxf(km, __shfl_xor(km, m, 64));
  if (lane == 0) sm[wave] = km;
  __syncthreads();
  const float xmax = fmaxf(fmaxf(sm[0], sm[1]), fmaxf(sm[2], sm[3])) + 1e-8f;
  const float Bk = 11.313708499f * ((3.5f + qjl[0] * xmax) * xmax / 3.5f) * 1.02f * 0.5f;

  // Q fragments, B-layout of 32x32x16 (pre-scaled by log2e/sqrt(128))
  bf16x8 qf[8];
#pragma unroll
  for (int t = 0; t < 8; ++t)
    qf[t] = *(const bf16x8*)&qb[(hrow + qrow0 + r31) * DH + t * 16 + hi * 8];
  const float mqneg = -(qn[hrow + qrow0 + r31] * Bk);   // log2-domain bound

  // Ks LDS read byte-offsets (tile-invariant): chunk (2t+hi) XOR (row&7)
  int koff[8];
#pragma unroll
  for (int t = 0; t < 8; ++t)
    koff[t] = r31 * 256 + (((2 * t + hi) ^ (r31 & 7)) << 4);

  // V LDS read byte-offsets per (half, dt)
  int vof0[4], vof1[4];
#pragma unroll
  for (int dt = 0; dt < 4; ++dt) {
    vof0[dt] = (((0 * 2 + hi) * 128) + dt * 32 + r31) * 16;
    vof1[dt] = (((1 * 2 + hi) * 128) + dt * 32 + r31) * 16;
  }

  // K DMA source (swizzle-compensated) / dest
  const __bf16* ksrc[2]; int kds[2];
#pragma unroll
  for (int u = 0; u < 2; ++u) {
    int c = (wave * 2 + u) * 64 + lane;
    int row = c >> 4, ch = (c & 15) ^ (row & 7);
    ksrc[u] = kd + (hrow + row) * DH + ch * 8;
    kds[u] = (wave * 2 + u) * 512;
  }
  // V DMA source: linear copy of the per-tile 8KB block
  const char* vbase = (const char*)(vdt2 + (long)head * 64 * 1024);
  const char* vsrc[2];
#pragma unroll
  for (int u = 0; u < 2; ++u)
    vsrc[u] = vbase + (long)((wave * 2 + u) * 64 + lane) * 16;

  // stage pair P (tiles 2P, 2P+1) into buffer B: 8 DMAs/thread
  auto STAGE = [&](int B, int P) {
    const long k0 = (long)(2 * P) * 32 * DH, k1 = k0 + 32 * DH;
    const long v0 = (long)(2 * P) * 8192,    v1 = v0 + 8192;
    lds_dma16(ksrc[0] + k0, &Ks[B][0][kds[0]]);
    lds_dma16(ksrc[1] + k0, &Ks[B][0][kds[1]]);
    lds_dma16(ksrc[0] + k1, &Ks[B][1][kds[0]]);
    lds_dma16(ksrc[1] + k1, &Ks[B][1][kds[1]]);
    lds_dma16(vsrc[0] + v0, &Vt[B][0][(wave * 2 + 0) * 128]);
    lds_dma16(vsrc[1] + v0, &Vt[B][0][(wave * 2 + 1) * 128]);
    lds_dma16(vsrc[0] + v1, &Vt[B][1][(wave * 2 + 0) * 128]);
    lds_dma16(vsrc[1] + v1, &Vt[B][1][(wave * 2 + 1) * 128]);
  };

  // prologue: stage pairs 0 and 1; wait pair 0 only
  STAGE(0, 0);
  STAGE(1, 1);
  asm volatile("s_waitcnt vmcnt(8)" ::: "memory");
  __builtin_amdgcn_s_barrier();
  asm volatile("" ::: "memory");

  f32x16 acc[4];
#pragma unroll
  for (int dt = 0; dt < 4; ++dt) acc[dt] = zero16();
  float ls0 = 0.f, ls1 = 0.f, ls2 = 0.f, ls3 = 0.f;

  // softmax + PV for one tile (P fragments feed x16 PV directly)
  auto TILE = [&](const f32x16& sa, const f32x16& sb, int B, int j) {
    float p[16];
#pragma unroll
    for (int r = 0; r < 16; ++r) p[r] = __builtin_amdgcn_exp2f(sa[r] + sb[r]);
#pragma unroll
    for (int r = 0; r < 16; r += 4) {
      ls0 += p[r]; ls1 += p[r + 1]; ls2 += p[r + 2]; ls3 += p[r + 3];
    }
    bf16x8 pa, pb;
#pragma unroll
    for (int jj = 0; jj < 8; ++jj) { pa[jj] = (__bf16)p[jj]; pb[jj] = (__bf16)p[8 + jj]; }
    const char* vb = (const char*)&Vt[B][j][0];
    __builtin_amdgcn_s_setprio(1);
#pragma unroll
    for (int dt = 0; dt < 4; ++dt) {
      bf16x8 v0 = *(const bf16x8*)(vb + vof0[dt]);
      acc[dt] = mfma_bf16_32x32x16(pa, v0, acc[dt]);
    }
#pragma unroll
    for (int dt = 0; dt < 4; ++dt) {
      bf16x8 v1 = *(const bf16x8*)(vb + vof1[dt]);
      acc[dt] = mfma_bf16_32x32x16(pb, v1, acc[dt]);
    }
    __builtin_amdgcn_s_setprio(0);
  };

#pragma unroll 1
  for (int i = 0; i < SLEN / 64; ++i) {
    const int B = i & 1;
    const char* k0 = (const char*)&Ks[B][0][0];
    const char* k1 = (const char*)&Ks[B][1][0];

    // S^T = K Q^T, 4 interleaved chains; sb accumulators start at -Mq
    f32x16 sa0 = zero16(), sa1 = zero16(), sb0, sb1;
#pragma unroll
    for (int r = 0; r < 16; ++r) { sb0[r] = mqneg; sb1[r] = mqneg; }
    __builtin_amdgcn_s_setprio(1);
#pragma unroll
    for (int t = 0; t < 8; t += 2) {
      bf16x8 ka0 = *(const bf16x8*)(k0 + koff[t]);
      bf16x8 kb0 = *(const bf16x8*)(k1 + koff[t]);
      bf16x8 ka1 = *(const bf16x8*)(k0 + koff[t + 1]);
      bf16x8 kb1 = *(const bf16x8*)(k1 + koff[t + 1]);
      sa0 = mfma_bf16_32x32x16(ka0, qf[t], sa0);
      sa1 = mfma_bf16_32x32x16(kb0, qf[t], sa1);
      sb0 = mfma_bf16_32x32x16(ka1, qf[t + 1], sb0);
      sb1 = mfma_bf16_32x32x16(kb1, qf[t + 1], sb1);
    }
    __builtin_amdgcn_s_setprio(0);

    TILE(sa0, sb0, B, 0);
    TILE(sa1, sb1, B, 1);

    if (i < SLEN / 64 - 1) {
      asm volatile("s_waitcnt vmcnt(0)" ::: "memory");   // pair i+1 landed
      __builtin_amdgcn_s_barrier();                      // raw: no drain
      asm volatile("" ::: "memory");
      if (i < SLEN / 64 - 2) STAGE(B, i + 2);
    }
  }

  float lsum = (ls0 + ls1) + (ls2 + ls3);
  lsum += __shfl_xor(lsum, 32, 64);
  if (hi == 0) Ls[wave][r31] = 1.0f / lsum;
  __syncthreads();            // all waves out of main loop; LDS free for reuse

  // ---- fused final rotation: OUT = O @ R^T (rot_o addressing) ----
  _Float16* BHR = (_Float16*)&Ks[0][0][0];            // 32KB: Bhi staged
  _Float16* Osh = (_Float16*)&Vt[0][0][0] + wave * 4096;  // 8KB/wave: O^f16

  // stage Bhi (row-major R), standard swizzled DMA pattern
#pragma unroll
  for (int u = 0; u < 8; ++u) {
    int c = (wave * 8 + u) * 64 + lane;
    int n = c >> 4, ch = (c & 15) ^ (n & 7);
    lds_dma16(Bhi + n * 128 + ch * 8, BHR + (wave * 8 + u) * 512);
  }

  // normalize O, write f16 into swizzled Osh: row q', chunk (d>>3)^(q'&7)
#pragma unroll
  for (int dt = 0; dt < 4; ++dt)
#pragma unroll
    for (int r = 0; r < 16; ++r) {
      int q2 = (r & 3) + 8 * (r >> 2) + 4 * hi;
      _Float16 o = (_Float16)(acc[dt][r] * Ls[wave][q2]);
      int ch = (dt * 4 + (r31 >> 3)) ^ (q2 & 7);
      Osh[q2 * 128 + ch * 8 + (r31 & 7)] = o;
    }
  __syncthreads();            // drains DMA (vmcnt 0) + ds_writes

  // A-frags from Osh (row = r31), B-frags from BHR, 32 MFMAs
  f16x8 ah[8];
#pragma unroll
  for (int t = 0; t < 8; ++t)
    ah[t] = *(const f16x8*)&Osh[r31 * 128 + (((2 * t + hi) ^ (r31 & 7)) * 8)];

  f32x16 acc2[4];
#pragma unroll
  for (int ct = 0; ct < 4; ++ct) acc2[ct] = zero16();
#pragma unroll
  for (int ct = 0; ct < 4; ++ct) {
#pragma unroll
    for (int t = 0; t < 8; ++t) {
      f16x8 bh = *(const f16x8*)&BHR[(ct * 32 + r31) * 128 +
                                     (((2 * t + hi) ^ (r31 & 7)) * 8)];
      acc2[ct] = mfma_f16_32x32x16(ah[t], bh, acc2[ct]);
    }
  }
#pragma unroll
  for (int ct = 0; ct < 4; ++ct)
#pragma unroll
    for (int r = 0; r < 16; ++r) {
      int m2 = (r & 3) + 8 * (r >> 2) + 4 * hi;
      OUT[(hrow + qrow0 + m2) * DH + ct * 32 + r31] = acc2[ct][r];
    }
}

// ---------------------------------------------------------------------------
extern "C" void kernel_launch(void* const* d_in, const int* in_sizes, int n_in,
                              void* d_out, int out_size, void* d_ws, size_t ws_size,
                              hipStream_t stream)
{
  const float* q   = (const float*)d_in[0];
  const float* k   = (const float*)d_in[1];
  const float* v   = (const float*)d_in[2];
  const float* R   = (const float*)d_in[3];
  const float* qjl = (const float*)d_in[4];

  char* ws = (char*)d_ws;
  float* kpart = (float*)ws;                      // [2048]
  float* vpart = (float*)(ws + 8192);             // [2048]
  _Float16* Bhi  = (_Float16*)(ws + 32768);       // R row-major f16 hi (32KB)
  _Float16* Blo  = (_Float16*)(ws + 65536);
  _Float16* BhiT = (_Float16*)(ws + 98304);       // R^T f16 hi
  _Float16* BloT = (_Float16*)(ws + 131072);
  float* qn = (float*)(ws + 163840);              // [65536] (256KB)
  char* base = ws + 425984;
  __bf16* qb   = (__bf16*)base;                                 // 16 MiB
  float*  kr   = (float*)(base + (16u << 20));                  // 32 MiB
  float*  vr   = (float*)(base + (48u << 20));                  // 32 MiB
  u64*    vdt2 = (u64*)(base + (80u << 20));                    // 16 MiB
  __bf16* kd   = (__bf16*)vr;       // reuse vr after quantize_vt consumed it

  dim3 b256(256);
  prep_R<<<64, b256, 0, stream>>>(R, Bhi, Blo, BhiT, BloT);
  rot_all_kernel<<<1536, b256, 0, stream>>>(k, v, q, BhiT, BloT, kr, vr,
                                            kpart, vpart, qb, qn);
  quantize_vt_kernel<<<2048, b256, 0, stream>>>(vr, vpart, qjl, vdt2);
  quantize_k_kernel<<<2048, b256, 0, stream>>>(kr, kpart, qjl, kd);
  attn2<<<512, b256, 0, stream>>>(qb, kd, vdt2, qn, kpart, qjl, Bhi,
                                  (float*)d_out);
}